// Round 10
// baseline (1574.441 us; speedup 1.0000x reference)
//
#include <hip/hip_runtime.h>
#include <hip/hip_fp16.h>

#define NH 4
#define HD 64
#define MF 266
#define MP 288           // MF padded to multiple of 32 for MFMA K-steps
#define NB 192           // k_ctx partial blocks
#define NBQ 128          // k_qattn blocks per head (grid-stride)
#define DN 0.35355339059327373f
#define RATIO 0.06131393394849658f
#define EPSRF 1e-4f
#define REPS (RATIO*EPSRF)

typedef unsigned short u16;
typedef unsigned int u32;
typedef __attribute__((ext_vector_type(8))) short bf16x8;
typedef __attribute__((ext_vector_type(4))) float f32x4;
#define MFMA16(a,b,c) __builtin_amdgcn_mfma_f32_16x16x32_bf16(a,b,c,0,0,0)

__device__ __forceinline__ float bf2f(u16 u){ return __uint_as_float(((u32)u)<<16); }
__device__ __forceinline__ u16 f2bf(float f){ u32 u = __float_as_uint(f); u += 0x7FFFu + ((u>>16)&1u); return (u16)(u>>16); }
__device__ __forceinline__ u32 pack2bf(float a, float b){ return ((u32)f2bf(b)<<16) | f2bf(a); }
__device__ __forceinline__ float eluf(float x){ return x>0.f ? x : (expf(x)-1.f); }

// ---------------- weight/proj conversion to bf16 ----------------
__global__ void k_cvtw(const float* __restrict__ qw, const float* __restrict__ kw,
                       const float* __restrict__ vw, const float* __restrict__ lw,
                       const float* __restrict__ l2w, const float* __restrict__ proj,
                       u16* __restrict__ Wb, u16* __restrict__ projp, u16* __restrict__ l2wb){
  int i = blockIdx.x*256 + threadIdx.x;
  if (i < 262144){
    int sec = i>>16, r = i&65535;
    const float* s = sec==0?qw : sec==1?kw : sec==2?vw : lw;
    Wb[i] = f2bf(s[r]);
  }
  if (i < MP*64){
    int r = i>>6, c = i&63;
    projp[i] = f2bf(r < MF ? proj[r*64 + c] : 0.f);
  }
  if (i < 32*512) l2wb[i] = f2bf(l2w[i]);
}

// ---------------- K1: fused projection GEMM (round-6 shape: 128-row X stage, 8 waves) ----------------
__global__ __launch_bounds__(512,4) void k_proj(
    const float* __restrict__ x, const u16* __restrict__ Wb,
    const float* __restrict__ qb, const float* __restrict__ kb,
    const float* __restrict__ vb, const float* __restrict__ lb,
    u16* __restrict__ Q, u16* __restrict__ K, u16* __restrict__ V,
    u16* __restrict__ G1, int n)
{
  __shared__ u32 Xs[128*128];   // [row][word 0..127], XOR-swizzled
  const int tid = threadIdx.x;
  const int w = tid>>6, l = tid&63;
  const int wr = w>>2, wc = w&3;
  const int lm = l&15, lk = l>>4;
  const int row0 = blockIdx.x*128;
  #pragma unroll 4
  for (int q=0;q<16;++q){
    int idx = q*512 + tid;          // 0..8191 float4s
    int r = idx>>6, c4 = idx&63;
    int rr = row0 + r; if (rr > n-1) rr = n-1;
    float4 v = *(const float4*)(x + (size_t)rr*256 + c4*4);
    int word = (c4*2) ^ ((r&7)<<2);
    *(uint2*)&Xs[r*128 + word] = make_uint2(pack2bf(v.x,v.y), pack2bf(v.z,v.w));
  }
  __syncthreads();
  #pragma unroll 1
  for (int ct=0; ct<8; ++ct){
    const int c0 = ct*128 + wc*32;
    f32x4 acc[4][2] = {};
    #pragma unroll 2
    for (int kt=0; kt<8; ++kt){
      bf16x8 Af[4], Bf[2];
      #pragma unroll
      for (int jj=0;jj<2;jj++)
        Bf[jj] = *(const bf16x8*)(Wb + (size_t)(c0 + jj*16 + lm)*256 + kt*32 + lk*8);
      #pragma unroll
      for (int i=0;i<4;i++){
        const int rl = wr*64 + i*16 + lm;
        Af[i] = *(const bf16x8*)&Xs[rl*128 + ((kt*16 + lk*4) ^ ((rl&7)<<2))];
      }
      #pragma unroll
      for (int i=0;i<4;i++)
        #pragma unroll
        for (int jj=0;jj<2;jj++)
          acc[i][jj] = MFMA16(Af[i], Bf[jj], acc[i][jj]);
    }
    const int sel = c0>>8;
    const float* bp = sel==0?qb : sel==1?kb : sel==2?vb : lb;
    u16* d3 = sel==0?Q : sel==1?K : sel==2?V : G1;
    u32* dst32 = (u32*)d3;
    const bool even = (lm&1)==0;
    #pragma unroll
    for (int jj=0;jj<2;jj++){
      const int cc = (c0&255) + jj*16 + lm;
      const float bias = bp[cc];
      const int ccA = cc & ~1;
      const int hh = ccA>>6, dd = ccA&63;
      #pragma unroll
      for (int i=0;i<4;i++){
        const int rb = row0 + wr*64 + i*16 + lk*4;
        u32 m01 = pack2bf(acc[i][jj][0]+bias, acc[i][jj][1]+bias);
        u32 m23 = pack2bf(acc[i][jj][2]+bias, acc[i][jj][3]+bias);
        u32 oa = __shfl_xor(m01,1);
        u32 ob = __shfl_xor(m23,1);
        u32 wA = even ? ((m01 & 0xffffu) | ((oa & 0xffffu)<<16))
                      : ((ob  & 0xffffu) | ((m23 & 0xffffu)<<16));
        u32 wB = even ? ((m01 >> 16) | (oa & 0xffff0000u))
                      : ((ob  >> 16) | (m23 & 0xffff0000u));
        const int rA = rb + (even ? 0 : 2);
        const int rB = rA + 1;
        if (sel==3){
          if (rA < n) dst32[(size_t)rA*128 + (ccA>>1)] = wA;
          if (rB < n) dst32[(size_t)rB*128 + (ccA>>1)] = wB;
        } else {
          if (rA < n) dst32[(((size_t)hh*n + rA)<<5) + (dd>>1)] = wA;
          if (rB < n) dst32[(((size_t)hh*n + rB)<<5) + (dd>>1)] = wB;
        }
      }
    }
  }
}

// ---------------- V column sums (for EPS correction) ----------------
__global__ void k_vcs(const u16* __restrict__ Vb, float* __restrict__ vcs, int n){
  const int h = blockIdx.y, tid = threadIdx.x;
  const int d = tid&63, seg = tid>>6;
  float s = 0.f;
  for (int node = blockIdx.x*4 + seg; node < n; node += 256)
    s += bf2f(Vb[(((size_t)h*n + node)<<6) + d]);
  __shared__ float sm[4][64];
  sm[seg][d] = s; __syncthreads();
  if (tid < 64){
    float t2 = sm[0][tid]+sm[1][tid]+sm[2][tid]+sm[3][tid];
    atomicAdd(vcs + h*64 + tid, t2);
  }
}

// ---------------- K3: single-pass kp -> ksum0/ctx0 partials + global dash max ----------------
__global__ __launch_bounds__(256) void k_ctx(
    const u16* __restrict__ Kb, const u16* __restrict__ Vb,
    const u16* __restrict__ projp,
    float* __restrict__ ctxp, float* __restrict__ ksump,
    u32* __restrict__ kmaxg, int n)
{
  __shared__ u32 kpT[288*32];     // kp^T [m][node-word], XOR-swizzled
  __shared__ u16 Vt[64][72];      // V^T tile [d][node]
  __shared__ float redk[4][288];
  const int tid = threadIdx.x;
  const int w = tid>>6, l = tid&63;
  const int bb = blockIdx.x;
  const int h = blockIdx.y;
  const int lm = l&15, lk = l>>4;
  f32x4 cacc[18] = {};
  float ksa[18] = {};
  float mreg = -3.0e38f;
  const int ntile = (n+63)>>6;
  #pragma unroll 1
  for (int t=bb; t<ntile; t+=NB){
    const int n0 = t*64;
    __syncthreads();
    #pragma unroll
    for (int q=0;q<2;q++){
      int e8 = tid + q*256;
      int nn = e8>>3, d0 = (e8&7)*8;
      uint4 rv = make_uint4(0,0,0,0);
      if (n0+nn < n) rv = *(const uint4*)(Vb + (((size_t)h*n + n0+nn)<<6) + d0);
      const u16* pv = (const u16*)&rv;
      #pragma unroll
      for (int s=0;s<8;s++) Vt[d0+s][nn] = pv[s];
    }
    int rr = n0 + w*16 + lm; if (rr > n-1) rr = n-1;
    const u16* Kbase = Kb + (((size_t)h*n + rr)<<6);
    bf16x8 af0 = *(const bf16x8*)(Kbase + lk*8);
    bf16x8 af1 = *(const bf16x8*)(Kbase + 32 + lk*8);
    float dg = 0.f;
    #pragma unroll
    for (int i2=0;i2<8;i2++){
      float a = bf2f(((const u16*)&af0)[i2]);
      float b = bf2f(((const u16*)&af1)[i2]);
      dg += a*a + b*b;
    }
    dg += __shfl_xor(dg,16); dg += __shfl_xor(dg,32);
    dg *= 0.0625f;
    float dgr[4];
    #pragma unroll
    for (int j=0;j<4;j++) dgr[j] = __shfl(dg, lk*4+j, 16);
    #pragma unroll
    for (int mt=0; mt<18; ++mt){
      bf16x8 b0 = *(const bf16x8*)(projp + (size_t)(mt*16+lm)*64 + lk*8);
      bf16x8 b1 = *(const bf16x8*)(projp + (size_t)(mt*16+lm)*64 + 32 + lk*8);
      f32x4 D = {0,0,0,0};
      D = MFMA16(af0, b0, D);
      D = MFMA16(af1, b1, D);
      const int m = mt*16 + lm;
      const bool vm = m < MF;
      float colsum = 0.f;
      u32 pk0 = 0, pk1 = 0;
      #pragma unroll
      for (int j=0;j<4;j++){
        float ddash = DN * D[j];
        float kp = 0.f;
        if (vm && (n0 + w*16 + lk*4 + j) < n){
          kp = RATIO * __expf(ddash - dgr[j]);
          mreg = fmaxf(mreg, ddash);
          colsum += kp;
        }
        if (j<2) pk0 |= ((u32)f2bf(kp)) << (16*j);
        else     pk1 |= ((u32)f2bf(kp)) << (16*(j-2));
      }
      const int wn0 = w*8 + lk*2;
      *(uint2*)&kpT[m*32 + (wn0 ^ ((m&7)<<2))] = make_uint2(pk0, pk1);
      colsum += __shfl_xor(colsum,16); colsum += __shfl_xor(colsum,32);
      ksa[mt] += colsum;
    }
    __syncthreads();
    #pragma unroll
    for (int mt=0; mt<18; ++mt){
      const int m = mt*16 + lm;
      #pragma unroll
      for (int ks=0;ks<2;++ks){
        bf16x8 a = *(const bf16x8*)&kpT[m*32 + ((ks*16 + lk*4) ^ ((m&7)<<2))];
        bf16x8 bv = *(const bf16x8*)&Vt[w*16+lm][ks*32 + lk*8];
        cacc[mt] = MFMA16(a, bv, cacc[mt]);
      }
    }
  }
  float* cp = ctxp + ((size_t)(h*NB + bb))*MP*64;
  #pragma unroll
  for (int mt=0;mt<18;++mt){
    #pragma unroll
    for (int j=0;j<4;j++){
      int m = mt*16 + lk*4 + j;
      cp[(size_t)m*64 + w*16 + lm] = cacc[mt][j];
    }
  }
  if (l < 16){
    #pragma unroll
    for (int mt=0;mt<18;++mt) redk[w][mt*16+lm] = ksa[mt];
  }
  __shared__ float redm[4];
  float mr = mreg;
  #pragma unroll
  for (int s=1;s<64;s<<=1) mr = fmaxf(mr, __shfl_xor(mr, s));
  if (l==0) redm[w] = mr;
  __syncthreads();
  for (int m2=tid; m2<MP; m2+=256){
    float s = redk[0][m2]+redk[1][m2]+redk[2][m2]+redk[3][m2];
    ksump[((size_t)(h*NB+bb))*MP + m2] = s;
  }
  if (tid==0){
    float bm = fmaxf(fmaxf(redm[0],redm[1]), fmaxf(redm[2],redm[3]));
    u32 b = __float_as_uint(bm);
    u32 enc = (b & 0x80000000u) ? ~b : (b | 0x80000000u);
    atomicMax(kmaxg + h, enc);
  }
}

// ---------------- K3b: reduce partials + apply max/EPS correction ----------------
__global__ void k_reduce(const float* __restrict__ ctxp, const float* __restrict__ ksump,
                         const u32* __restrict__ kmaxg, const float* __restrict__ vcs,
                         u16* __restrict__ ctxT, float* __restrict__ ksum, int n)
{
  const int T1 = NH*MP*64;
  int idx = blockIdx.x*256 + threadIdx.x;
  if (idx < T1){
    int h = idx/(MP*64), r = idx - h*MP*64, m = r>>6, d = r&63;
    u32 ee = kmaxg[h]; u32 b = (ee & 0x80000000u) ? (ee ^ 0x80000000u) : ~ee;
    float sc = __expf(-__uint_as_float(b));
    float s = 0.f;
    for (int bb=0; bb<NB; ++bb) s += ctxp[(((size_t)(h*NB+bb))*MP + m)*64 + d];
    float val = (m < MF) ? (sc*s + REPS*vcs[h*64 + d]) : 0.f;
    ctxT[((size_t)h*64 + d)*MP + m] = f2bf(val);
  } else if (idx < T1 + NH*MP){
    int k2 = idx - T1, h = k2/MP, m = k2 - h*MP;
    u32 ee = kmaxg[h]; u32 b = (ee & 0x80000000u) ? (ee ^ 0x80000000u) : ~ee;
    float sc = __expf(-__uint_as_float(b));
    float s = 0.f;
    for (int bb=0; bb<NB; ++bb) s += ksump[((size_t)(h*NB+bb))*MP + m];
    ksum[h*MP + m] = (m < MF) ? (sc*s + REPS*(float)n) : 0.f;
  }
}

// ---------------- K4: query path (MFMA, proj staged in LDS, grid-stride tiles) ----------------
__global__ __launch_bounds__(256) void k_qattn(
    const u16* __restrict__ Qb, const u16* __restrict__ projp,
    const u16* __restrict__ ctxT, const float* __restrict__ ksum,
    u16* __restrict__ trans, int n)
{
  __shared__ u32 pj[288*32];              // swizzled proj (36864 B)
  __shared__ u16 qp_lds[4][16][168];      // per-wave qp half (21504 B)
  const int tid = threadIdx.x;
  const int w = tid>>6, l = tid&63;
  const int h = blockIdx.y;
  const int lm = l&15, lk = l>>4;
  #pragma unroll
  for (int q=0; q<9; ++q){
    int cix = q*256 + tid;
    int row = cix>>3, c4 = (cix&7)*4;
    uint4 v = *(const uint4*)(projp + row*64 + c4*2);
    *(uint4*)&pj[row*32 + (c4 ^ ((row&7)<<2))] = v;
  }
  float ksm[18];
  #pragma unroll
  for (int mt=0;mt<18;++mt) ksm[mt] = ksum[h*MP + mt*16 + lm];
  __syncthreads();
  const int ntile = (n+63)>>6;
  #pragma unroll 1
  for (int t = blockIdx.x; t < ntile; t += NBQ){
    const int nb = t*64 + w*16;
    int rr = nb + lm; if (rr > n-1) rr = n-1;
    const u16* Qbase = Qb + (((size_t)h*n + rr)<<6);
    bf16x8 af0 = *(const bf16x8*)(Qbase + lk*8);
    bf16x8 af1 = *(const bf16x8*)(Qbase + 32 + lk*8);
    float dg = 0.f;
    #pragma unroll
    for (int i2=0;i2<8;i2++){
      float a = bf2f(((const u16*)&af0)[i2]);
      float b = bf2f(((const u16*)&af1)[i2]);
      dg += a*a + b*b;
    }
    dg += __shfl_xor(dg,16); dg += __shfl_xor(dg,32);
    dg *= 0.0625f;
    float dgr[4];
    #pragma unroll
    for (int j=0;j<4;j++) dgr[j] = __shfl(dg, lk*4+j, 16);
    f32x4 D[18];
    #pragma unroll
    for (int mt=0;mt<18;++mt){
      const int m = mt*16 + lm;
      bf16x8 b0 = *(const bf16x8*)&pj[m*32 + ((lk*4) ^ ((m&7)<<2))];
      bf16x8 b1 = *(const bf16x8*)&pj[m*32 + ((16 + lk*4) ^ ((m&7)<<2))];
      f32x4 z = {0,0,0,0};
      z = MFMA16(af0, b0, z);
      z = MFMA16(af1, b1, z);
      D[mt] = z;
    }
    float rmax[4] = {-3.0e38f,-3.0e38f,-3.0e38f,-3.0e38f};
    #pragma unroll
    for (int mt=0;mt<17;++mt){
      const bool vm = (mt<16) || (lm<10);
      #pragma unroll
      for (int j=0;j<4;j++){
        float dd = DN*D[mt][j];
        if (vm) rmax[j] = fmaxf(rmax[j], dd);
      }
    }
    #pragma unroll
    for (int j=0;j<4;j++){
      #pragma unroll
      for (int s=1;s<16;s<<=1) rmax[j] = fmaxf(rmax[j], __shfl_xor(rmax[j], s));
    }
    float den[4] = {0,0,0,0};
    f32x4 o[4] = {{0,0,0,0},{0,0,0,0},{0,0,0,0},{0,0,0,0}};
    #pragma unroll
    for (int mt=0;mt<10;++mt){
      #pragma unroll
      for (int j=0;j<4;j++){
        float qp = RATIO*(__expf(DN*D[mt][j] - dgr[j] - rmax[j]) + EPSRF);
        den[j] += qp * ksm[mt];
        qp_lds[w][lk*4+j][mt*16+lm] = f2bf(qp);
      }
    }
    #pragma unroll
    for (int ks=0;ks<5;++ks){
      bf16x8 av = *(const bf16x8*)&qp_lds[w][lm][ks*32 + lk*8];
      #pragma unroll
      for (int dt=0;dt<4;++dt){
        bf16x8 bv = *(const bf16x8*)(ctxT + (size_t)(h*64 + dt*16 + lm)*MP + ks*32 + lk*8);
        o[dt] = MFMA16(av, bv, o[dt]);
      }
    }
    #pragma unroll
    for (int mt=10;mt<18;++mt){
      #pragma unroll
      for (int j=0;j<4;j++){
        float qp = RATIO*(__expf(DN*D[mt][j] - dgr[j] - rmax[j]) + EPSRF);
        den[j] += qp * ksm[mt];
        qp_lds[w][lk*4+j][(mt-10)*16+lm] = f2bf(qp);
      }
    }
    #pragma unroll
    for (int ks=5;ks<9;++ks){
      bf16x8 av = *(const bf16x8*)&qp_lds[w][lm][(ks-5)*32 + lk*8];
      #pragma unroll
      for (int dt=0;dt<4;++dt){
        bf16x8 bv = *(const bf16x8*)(ctxT + (size_t)(h*64 + dt*16 + lm)*MP + ks*32 + lk*8);
        o[dt] = MFMA16(av, bv, o[dt]);
      }
    }
    #pragma unroll
    for (int j=0;j<4;j++){
      #pragma unroll
      for (int s=1;s<16;s<<=1) den[j] += __shfl_xor(den[j], s);
    }
    #pragma unroll
    for (int j=0;j<4;j++){
      const int node = nb + lk*4 + j;
      if (node < n){
        const float dv = 1.f/den[j];
        #pragma unroll
        for (int dt=0;dt<4;++dt)
          trans[(size_t)node*256 + h*64 + dt*16 + lm] = f2bf(o[dt][j]*dv);
      }
    }
  }
}

// ---------------- K5: cat -> elu -> lin2 -> elu (MFMA) ----------------
__global__ __launch_bounds__(256) void k_gnn2(
    const u16* __restrict__ G1, const u16* __restrict__ trans,
    const u16* __restrict__ l2wb, const float* __restrict__ l2b,
    u16* __restrict__ xb0, int n)
{
  __shared__ u32 cat[64*256];   // 64 nodes x 512 bf16, swizzled
  const int tid = threadIdx.x;
  const int w = tid>>6, l = tid&63;
  const int lm = l&15, lk = l>>4;
  const int n0 = blockIdx.x*64;
  #pragma unroll
  for (int src=0; src<2; ++src){
    const u16* S = src ? trans : G1;
    #pragma unroll
    for (int q=0;q<8;++q){
      int idx = q*256 + tid;
      int row = idx>>5, v8 = idx&31;
      int rr = n0+row; if (rr > n-1) rr = n-1;
      uint4 raw = *(const uint4*)(S + (size_t)rr*256 + v8*8);
      const u16* p = (const u16*)&raw;
      u32 o2[4];
      #pragma unroll
      for (int t2=0;t2<4;++t2)
        o2[t2] = pack2bf(eluf(bf2f(p[t2*2])), eluf(bf2f(p[t2*2+1])));
      int word = (v8*4 + src*128) ^ ((row&7)<<2);
      *(uint4*)&cat[row*256 + word] = *(uint4*)o2;
    }
  }
  __syncthreads();
  f32x4 acc[2] = {{0,0,0,0},{0,0,0,0}};
  const int rowl = w*16 + lm;
  #pragma unroll 4
  for (int kt=0; kt<16; ++kt){
    bf16x8 a = *(const bf16x8*)&cat[rowl*256 + ((kt*16 + lk*4) ^ ((rowl&7)<<2))];
    #pragma unroll
    for (int jj=0;jj<2;++jj){
      bf16x8 b = *(const bf16x8*)(l2wb + (size_t)(jj*16+lm)*512 + kt*32 + lk*8);
      acc[jj] = MFMA16(a, b, acc[jj]);
    }
  }
  #pragma unroll
  for (int jj=0;jj<2;++jj){
    const int o = jj*16 + lm;
    const float bias = l2b[o];
    #pragma unroll
    for (int jr=0;jr<4;++jr){
      const int node = n0 + w*16 + lk*4 + jr;
      if (node < n)
        xb0[(size_t)node*32 + o] = f2bf(eluf(acc[jj][jr] + bias));
    }
  }
}

// ---------------- edge layout detect ----------------
__global__ void k_edgemode(const int* __restrict__ ei, int* __restrict__ mode){
  __shared__ int any;
  if (threadIdx.x==0) any = 0;
  __syncthreads();
  if (ei[threadIdx.x*2+1] != 0) any = 1;
  __syncthreads();
  if (threadIdx.x==0) *mode = any;
}
__device__ __forceinline__ int edge_at(const int* ei, int mode, size_t idx){
  if (mode) return ei[idx];
  return (int)((const long long*)ei)[idx];
}

// ---------------- CSR build ----------------
__global__ void k_hist(const int* __restrict__ ei, const int* __restrict__ mode,
                       u32* __restrict__ deg, int e){
  const int md = *mode;
  for (size_t i = (size_t)blockIdx.x*blockDim.x + threadIdx.x; i < (size_t)e; i += (size_t)gridDim.x*blockDim.x)
    atomicAdd(&deg[edge_at(ei, md, (size_t)e + i)], 1u);
}
__global__ void k_dis(const u32* __restrict__ deg, float* __restrict__ dis, int n){
  int i = blockIdx.x*256 + threadIdx.x;
  if (i<n) dis[i] = rsqrtf((float)(deg[i] + 1u));
}
__global__ __launch_bounds__(1024) void k_scan(const u32* __restrict__ deg, u32* __restrict__ rowp, int n){
  __shared__ u32 wsum[16];
  __shared__ u32 carry;
  const int tid = threadIdx.x, lane = tid&63, wv = tid>>6;
  if (tid==0){ carry = 0u; rowp[0] = 0u; }
  __syncthreads();
  for (int base=0; base<n; base+=1024){
    int i = base + tid;
    u32 v = (i<n)? deg[i] : 0u;
    u32 s = v;
    #pragma unroll
    for (int off=1; off<64; off<<=1){
      u32 t = __shfl_up(s, off, 64);
      if (lane >= off) s += t;
    }
    if (lane==63) wsum[wv] = s;
    __syncthreads();
    if (wv==0){
      u32 ws = (lane<16)? wsum[lane] : 0u;
      #pragma unroll
      for (int off=1; off<16; off<<=1){
        u32 t = __shfl_up(ws, off, 64);
        if (lane >= off) ws += t;
      }
      if (lane<16) wsum[lane] = ws;
    }
    __syncthreads();
    u32 pre = carry + (wv ? wsum[wv-1] : 0u);
    if (i<n) rowp[i+1] = pre + s;
    __syncthreads();
    if (tid==0) carry += wsum[15];
    __syncthreads();
  }
}
__global__ void k_copy(const u32* __restrict__ a, u32* __restrict__ b, int n){
  int i = blockIdx.x*256 + threadIdx.x; if (i<n) b[i]=a[i];
}
__global__ void k_fill(const int* __restrict__ ei, const int* __restrict__ mode,
                       const float* __restrict__ dis,
                       u32* __restrict__ cur, uint2* __restrict__ cw, int e){
  const int md = *mode;
  for (size_t i = (size_t)blockIdx.x*blockDim.x + threadIdx.x; i < (size_t)e; i += (size_t)gridDim.x*blockDim.x){
    int s = edge_at(ei, md, i);
    int t = edge_at(ei, md, (size_t)e + i);
    u32 pos = atomicAdd(&cur[t], 1u);
    cw[pos] = make_uint2((u32)s, __float_as_uint(dis[s]*dis[t]));
  }
}

// ---------------- window-local degree sort (256-node windows, stable counting sort) ----------------
// Groups nodes of similar degree into the same wave in k_appnp -> less divergence waste.
__global__ __launch_bounds__(256) void k_dperm(const u32* __restrict__ rowp,
                                               u32* __restrict__ perm, int n){
  __shared__ u32 keys[256];
  __shared__ u32 hist[256];
  __shared__ u32 scn[256];
  const int tid = threadIdx.x;
  const int base = blockIdx.x*256;
  const int node = base + tid;
  u32 key = 255u;
  if (node < n){
    u32 d = rowp[node+1] - rowp[node];
    key = d > 254u ? 254u : d;
  }
  keys[tid] = key;
  hist[tid] = 0u;
  __syncthreads();
  atomicAdd(&hist[key], 1u);
  __syncthreads();
  u32 sv = hist[tid];
  scn[tid] = sv;
  __syncthreads();
  for (int off=1; off<256; off<<=1){
    u32 t = (tid>=off)? scn[tid-off] : 0u;
    __syncthreads();
    scn[tid] += t;
    __syncthreads();
  }
  // stable rank within bin
  u32 r = 0;
  for (int j=0;j<tid;++j) if (keys[j]==key) ++r;
  u32 pos = scn[key] - hist[key] + r;   // exclusive offset + rank
  perm[base + pos] = (u32)node;         // nodes>=n carry key 255 -> sorted last; APPNP guards
}

// ---------------- APPNP iteration (8 lanes/node, degree-sorted perm, uint2 gathers) ----------------
__global__ __launch_bounds__(256) void k_appnp(
    const u16* __restrict__ xin, const u16* __restrict__ hb16,
    u16* __restrict__ xout, const u32* __restrict__ rowp,
    const uint2* __restrict__ cw, const float* __restrict__ dis,
    const u32* __restrict__ perm, int n)
{
  const int g = threadIdx.x>>3, j4 = threadIdx.x&7;
  const int node = (int)perm[blockIdx.x*32 + g];
  if (node >= n) return;
  const uint2* x64 = (const uint2*)xin;
  float d0 = dis[node];
  float dd = d0*d0;
  uint2 xv = x64[((size_t)node<<3) + j4];
  float a0 = dd*bf2f((u16)xv.x), a1 = dd*bf2f((u16)(xv.x>>16));
  float a2 = dd*bf2f((u16)xv.y), a3 = dd*bf2f((u16)(xv.y>>16));
  u32 r0 = rowp[node], r1 = rowp[node+1];
  u32 k = r0;
  for (; k+4 <= r1; k += 4){
    uint2 e0 = cw[k], e1 = cw[k+1], e2 = cw[k+2], e3 = cw[k+3];
    uint2 v0 = x64[((size_t)e0.x<<3)+j4], v1 = x64[((size_t)e1.x<<3)+j4];
    uint2 v2 = x64[((size_t)e2.x<<3)+j4], v3 = x64[((size_t)e3.x<<3)+j4];
    float w0=__uint_as_float(e0.y), w1=__uint_as_float(e1.y);
    float w2=__uint_as_float(e2.y), w3=__uint_as_float(e3.y);
    a0 += w0*bf2f((u16)v0.x) + w1*bf2f((u16)v1.x) + w2*bf2f((u16)v2.x) + w3*bf2f((u16)v3.x);
    a1 += w0*bf2f((u16)(v0.x>>16)) + w1*bf2f((u16)(v1.x>>16)) + w2*bf2f((u16)(v2.x>>16)) + w3*bf2f((u16)(v3.x>>16));
    a2 += w0*bf2f((u16)v0.y) + w1*bf2f((u16)v1.y) + w2*bf2f((u16)v2.y) + w3*bf2f((u16)v3.y);
    a3 += w0*bf2f((u16)(v0.y>>16)) + w1*bf2f((u16)(v1.y>>16)) + w2*bf2f((u16)(v2.y>>16)) + w3*bf2f((u16)(v3.y>>16));
  }
  for (; k < r1; ++k){
    uint2 e = cw[k];
    uint2 v = x64[((size_t)e.x<<3)+j4];
    float wgt = __uint_as_float(e.y);
    a0 += wgt*bf2f((u16)v.x);
    a1 += wgt*bf2f((u16)(v.x>>16));
    a2 += wgt*bf2f((u16)v.y);
    a3 += wgt*bf2f((u16)(v.y>>16));
  }
  uint2 hv = ((const uint2*)hb16)[((size_t)node<<3) + j4];
  uint2 o;
  o.x = pack2bf(0.9f*a0 + 0.1f*bf2f((u16)hv.x), 0.9f*a1 + 0.1f*bf2f((u16)(hv.x>>16)));
  o.y = pack2bf(0.9f*a2 + 0.1f*bf2f((u16)hv.y), 0.9f*a3 + 0.1f*bf2f((u16)(hv.y>>16)));
  ((uint2*)xout)[((size_t)node<<3) + j4] = o;
}

// ---------------- final APPNP iteration fused with log_softmax + raw write ----------------
__global__ __launch_bounds__(256) void k_appnp_lsm(
    const u16* __restrict__ xin, const u16* __restrict__ hb16,
    float* __restrict__ out, const u32* __restrict__ rowp,
    const uint2* __restrict__ cw, const float* __restrict__ dis,
    const u32* __restrict__ perm, int n)
{
  const int g = threadIdx.x>>3, j4 = threadIdx.x&7;
  const int node = (int)perm[blockIdx.x*32 + g];
  if (node >= n) return;
  const uint2* x64 = (const uint2*)xin;
  float d0 = dis[node];
  float dd = d0*d0;
  uint2 xv = x64[((size_t)node<<3) + j4];
  float a0 = dd*bf2f((u16)xv.x), a1 = dd*bf2f((u16)(xv.x>>16));
  float a2 = dd*bf2f((u16)xv.y), a3 = dd*bf2f((u16)(xv.y>>16));
  u32 r0 = rowp[node], r1 = rowp[node+1];
  u32 k = r0;
  for (; k+4 <= r1; k += 4){
    uint2 e0 = cw[k], e1 = cw[k+1], e2 = cw[k+2], e3 = cw[k+3];
    uint2 v0 = x64[((size_t)e0.x<<3)+j4], v1 = x64[((size_t)e1.x<<3)+j4];
    uint2 v2 = x64[((size_t)e2.x<<3)+j4], v3 = x64[((size_t)e3.x<<3)+j4];
    float w0=__uint_as_float(e0.y), w1=__uint_as_float(e1.y);
    float w2=__uint_as_float(e2.y), w3=__uint_as_float(e3.y);
    a0 += w0*bf2f((u16)v0.x) + w1*bf2f((u16)v1.x) + w2*bf2f((u16)v2.x) + w3*bf2f((u16)v3.x);
    a1 += w0*bf2f((u16)(v0.x>>16)) + w1*bf2f((u16)(v1.x>>16)) + w2*bf2f((u16)(v2.x>>16)) + w3*bf2f((u16)(v3.x>>16));
    a2 += w0*bf2f((u16)v0.y) + w1*bf2f((u16)v1.y) + w2*bf2f((u16)v2.y) + w3*bf2f((u16)v3.y);
    a3 += w0*bf2f((u16)(v0.y>>16)) + w1*bf2f((u16)(v1.y>>16)) + w2*bf2f((u16)(v2.y>>16)) + w3*bf2f((u16)(v3.y>>16));
  }
  for (; k < r1; ++k){
    uint2 e = cw[k];
    uint2 v = x64[((size_t)e.x<<3)+j4];
    float wgt = __uint_as_float(e.y);
    a0 += wgt*bf2f((u16)v.x);
    a1 += wgt*bf2f((u16)(v.x>>16));
    a2 += wgt*bf2f((u16)v.y);
    a3 += wgt*bf2f((u16)(v.y>>16));
  }
  uint2 hv = ((const uint2*)hb16)[((size_t)node<<3) + j4];
  float v0 = 0.9f*a0 + 0.1f*bf2f((u16)hv.x);
  float v1 = 0.9f*a1 + 0.1f*bf2f((u16)(hv.x>>16));
  float v2 = 0.9f*a2 + 0.1f*bf2f((u16)hv.y);
  float v3 = 0.9f*a3 + 0.1f*bf2f((u16)(hv.y>>16));
  float m = fmaxf(fmaxf(v0,v1), fmaxf(v2,v3));
  #pragma unroll
  for (int o2=1;o2<8;o2<<=1) m = fmaxf(m, __shfl_xor(m, o2, 8));
  float s = __expf(v0-m)+__expf(v1-m)+__expf(v2-m)+__expf(v3-m);
  #pragma unroll
  for (int o2=1;o2<8;o2<<=1) s += __shfl_xor(s, o2, 8);
  float ls = m + logf(s);
  float4 lsv = make_float4(v0-ls, v1-ls, v2-ls, v3-ls);
  *(float4*)(out + (size_t)node*32 + j4*4) = lsv;
  float4 raw = make_float4(v0, v1, v2, v3);
  *(float4*)(out + (size_t)n*32 + (size_t)node*32 + j4*4) = raw;
}

extern "C" void kernel_launch(void* const* d_in, const int* in_sizes, int n_in,
                              void* d_out, int out_size, void* d_ws, size_t ws_size,
                              hipStream_t stream)
{
  const float* x   = (const float*)d_in[0];
  const int*   ei  = (const int*)  d_in[1];
  const float* l1w = (const float*)d_in[2];
  const float* l1b = (const float*)d_in[3];
  const float* l2w = (const float*)d_in[4];
  const float* l2b = (const float*)d_in[5];
  const float* qw  = (const float*)d_in[6];
  const float* qb  = (const float*)d_in[7];
  const float* kw  = (const float*)d_in[8];
  const float* kb  = (const float*)d_in[9];
  const float* vw  = (const float*)d_in[10];
  const float* vb  = (const float*)d_in[11];
  const float* proj= (const float*)d_in[12];
  const int n = in_sizes[0] / 256;
  const int e = in_sizes[1] / 2;

  char* ws = (char*)d_ws;
  auto au = [](size_t v){ return (v + 255) & ~(size_t)255; };
  const size_t bQ = (size_t)n * 512;
  const size_t oQ = 0;
  const size_t oK = au(oQ + bQ);
  const size_t oV = au(oK + bQ);
  const size_t oG1 = au(oV + bQ);
  const size_t oCtxp = au(oG1 + bQ);
  const size_t bCtxp = (size_t)NH*NB*MP*64*4;
  const size_t oKsump = au(oCtxp + bCtxp);
  const size_t bKsump = (size_t)NH*NB*MP*4;
  const size_t oCtxT = au(oKsump + bKsump);
  const size_t oKsum = au(oCtxT + (size_t)NH*64*MP*2);
  const size_t oKmax = au(oKsum + (size_t)NH*MP*4);
  const size_t oVcs  = oKmax + 256;
  const size_t oMode = oVcs + 1024;
  const size_t oL2wb = au(oMode + 256);
  const size_t oWb   = au(oL2wb + 32768);
  const size_t oProjp= au(oWb + (size_t)1024*256*2);
  const size_t oTrans = oK;
  const size_t oG2 = oQ;
  const size_t oXb0 = au(oG2 + (size_t)n*32*4);
  const size_t oXbA = au(oXb0 + (size_t)n*32*2);
  const size_t oXbB = au(oXbA + (size_t)n*32*2);
  const size_t oDeg = au(oXbB + (size_t)n*32*2);
  const size_t oDis = au(oDeg + (size_t)n*4);
  const size_t oRowp= au(oDis + (size_t)n*4);
  const size_t oCur = au(oRowp + (size_t)(n+1)*4);
  const int nwin = (n+255)/256;
  const size_t oPerm= au(oCur + (size_t)(n+1)*4);
  const size_t oCw  = oV;
  (void)ws_size; (void)n_in; (void)out_size;

  u16* Q  = (u16*)(ws + oQ);
  u16* Kb = (u16*)(ws + oK);
  u16* Vb = (u16*)(ws + oV);
  u16* G1 = (u16*)(ws + oG1);
  float* ctxp = (float*)(ws + oCtxp);
  float* ksump= (float*)(ws + oKsump);
  u16*  ctxT  = (u16*)(ws + oCtxT);
  float* ksum = (float*)(ws + oKsum);
  u32*  kmax  = (u32*)(ws + oKmax);
  float* Vcs  = (float*)(ws + oVcs);
  int*  mode  = (int*)(ws + oMode);
  u16*  l2wb  = (u16*)(ws + oL2wb);
  u16*  Wb    = (u16*)(ws + oWb);
  u16*  projp = (u16*)(ws + oProjp);
  u16* trans  = (u16*)(ws + oTrans);
  u16* xb0    = (u16*)(ws + oXb0);
  u16* xbA    = (u16*)(ws + oXbA);
  u16* xbB    = (u16*)(ws + oXbB);
  u32* deg    = (u32*)(ws + oDeg);
  float* dis  = (float*)(ws + oDis);
  u32* rowp   = (u32*)(ws + oRowp);
  u32* cur    = (u32*)(ws + oCur);
  u32* perm   = (u32*)(ws + oPerm);
  uint2* cw   = (uint2*)(ws + oCw);

  k_cvtw<<<1024,256,0,stream>>>(qw,kw,vw,l1w,l2w,proj,Wb,projp,l2wb);
  k_proj<<<(n+127)/128,512,0,stream>>>(x,Wb,qb,kb,vb,l1b,Q,Kb,Vb,G1,n);
  hipMemsetAsync(ws + oKmax, 0, 16, stream);
  hipMemsetAsync(ws + oVcs, 0, 1024, stream);
  k_vcs<<<dim3(64,4),256,0,stream>>>(Vb,Vcs,n);
  k_ctx<<<dim3(NB,NH),256,0,stream>>>(Kb,Vb,projp,ctxp,ksump,kmax,n);
  {
    int tot = NH*MP*64 + NH*MP;
    k_reduce<<<(tot+255)/256,256,0,stream>>>(ctxp,ksump,kmax,Vcs,ctxT,ksum,n);
  }
  k_qattn<<<dim3(NBQ,4),256,0,stream>>>(Q,projp,ctxT,ksum,trans,n);
  k_gnn2<<<(n+63)/64,256,0,stream>>>(G1,trans,l2wb,l2b,xb0,n);
  // ---- APPNP ----
  k_edgemode<<<1,256,0,stream>>>(ei,mode);
  hipMemsetAsync(ws + oDeg, 0, (size_t)n*4, stream);
  k_hist<<<2048,256,0,stream>>>(ei,mode,deg,e);
  k_dis<<<(n+255)/256,256,0,stream>>>(deg,dis,n);
  k_scan<<<1,1024,0,stream>>>(deg,rowp,n);
  k_copy<<<(n+255)/256,256,0,stream>>>(rowp,cur,n);
  k_fill<<<2048,256,0,stream>>>(ei,mode,dis,cur,cw,e);
  k_dperm<<<nwin,256,0,stream>>>(rowp,perm,n);
  const u16* curx = xb0;
  u16* bufs[2] = {xbA, xbB};
  for (int it=0; it<9; ++it){
    u16* nxt = bufs[it&1];
    k_appnp<<<(n+31)/32,256,0,stream>>>(curx,xb0,nxt,rowp,cw,dis,perm,n);
    curx = nxt;
  }
  k_appnp_lsm<<<(n+31)/32,256,0,stream>>>(curx,xb0,(float*)d_out,rowp,cw,dis,perm,n);
}

// Round 11
// 1404.154 us; speedup vs baseline: 1.1213x; 1.1213x over previous
//
#include <hip/hip_runtime.h>
#include <hip/hip_fp16.h>

#define NH 4
#define HD 64
#define MF 266
#define MP 288           // MF padded to multiple of 32 for MFMA K-steps
#define NB 192           // k_ctx partial blocks
#define NBQ 128          // k_qattn blocks per head (grid-stride)
#define DN 0.35355339059327373f
#define RATIO 0.06131393394849658f
#define EPSRF 1e-4f
#define REPS (RATIO*EPSRF)

typedef unsigned short u16;
typedef unsigned int u32;
typedef __attribute__((ext_vector_type(8))) short bf16x8;
typedef __attribute__((ext_vector_type(4))) float f32x4;
#define MFMA16(a,b,c) __builtin_amdgcn_mfma_f32_16x16x32_bf16(a,b,c,0,0,0)

__device__ __forceinline__ float bf2f(u16 u){ return __uint_as_float(((u32)u)<<16); }
__device__ __forceinline__ u16 f2bf(float f){ u32 u = __float_as_uint(f); u += 0x7FFFu + ((u>>16)&1u); return (u16)(u>>16); }
__device__ __forceinline__ u32 pack2bf(float a, float b){ return ((u32)f2bf(b)<<16) | f2bf(a); }
__device__ __forceinline__ float eluf(float x){ return x>0.f ? x : (expf(x)-1.f); }

// ---------------- weight/proj conversion to bf16 ----------------
__global__ void k_cvtw(const float* __restrict__ qw, const float* __restrict__ kw,
                       const float* __restrict__ vw, const float* __restrict__ lw,
                       const float* __restrict__ l2w, const float* __restrict__ proj,
                       u16* __restrict__ Wb, u16* __restrict__ projp, u16* __restrict__ l2wb){
  int i = blockIdx.x*256 + threadIdx.x;
  if (i < 262144){
    int sec = i>>16, r = i&65535;
    const float* s = sec==0?qw : sec==1?kw : sec==2?vw : lw;
    Wb[i] = f2bf(s[r]);
  }
  if (i < MP*64){
    int r = i>>6, c = i&63;
    projp[i] = f2bf(r < MF ? proj[r*64 + c] : 0.f);
  }
  if (i < 32*512) l2wb[i] = f2bf(l2w[i]);
}

// ---------------- K1: fused projection GEMM (round-6 shape: 128-row X stage, 8 waves) ----------------
__global__ __launch_bounds__(512,4) void k_proj(
    const float* __restrict__ x, const u16* __restrict__ Wb,
    const float* __restrict__ qb, const float* __restrict__ kb,
    const float* __restrict__ vb, const float* __restrict__ lb,
    u16* __restrict__ Q, u16* __restrict__ K, u16* __restrict__ V,
    u16* __restrict__ G1, int n)
{
  __shared__ u32 Xs[128*128];   // [row][word 0..127], XOR-swizzled
  const int tid = threadIdx.x;
  const int w = tid>>6, l = tid&63;
  const int wr = w>>2, wc = w&3;
  const int lm = l&15, lk = l>>4;
  const int row0 = blockIdx.x*128;
  #pragma unroll 4
  for (int q=0;q<16;++q){
    int idx = q*512 + tid;          // 0..8191 float4s
    int r = idx>>6, c4 = idx&63;
    int rr = row0 + r; if (rr > n-1) rr = n-1;
    float4 v = *(const float4*)(x + (size_t)rr*256 + c4*4);
    int word = (c4*2) ^ ((r&7)<<2);
    *(uint2*)&Xs[r*128 + word] = make_uint2(pack2bf(v.x,v.y), pack2bf(v.z,v.w));
  }
  __syncthreads();
  #pragma unroll 1
  for (int ct=0; ct<8; ++ct){
    const int c0 = ct*128 + wc*32;
    f32x4 acc[4][2] = {};
    #pragma unroll 2
    for (int kt=0; kt<8; ++kt){
      bf16x8 Af[4], Bf[2];
      #pragma unroll
      for (int jj=0;jj<2;jj++)
        Bf[jj] = *(const bf16x8*)(Wb + (size_t)(c0 + jj*16 + lm)*256 + kt*32 + lk*8);
      #pragma unroll
      for (int i=0;i<4;i++){
        const int rl = wr*64 + i*16 + lm;
        Af[i] = *(const bf16x8*)&Xs[rl*128 + ((kt*16 + lk*4) ^ ((rl&7)<<2))];
      }
      #pragma unroll
      for (int i=0;i<4;i++)
        #pragma unroll
        for (int jj=0;jj<2;jj++)
          acc[i][jj] = MFMA16(Af[i], Bf[jj], acc[i][jj]);
    }
    const int sel = c0>>8;
    const float* bp = sel==0?qb : sel==1?kb : sel==2?vb : lb;
    u16* d3 = sel==0?Q : sel==1?K : sel==2?V : G1;
    u32* dst32 = (u32*)d3;
    const bool even = (lm&1)==0;
    #pragma unroll
    for (int jj=0;jj<2;jj++){
      const int cc = (c0&255) + jj*16 + lm;
      const float bias = bp[cc];
      const int ccA = cc & ~1;
      const int hh = ccA>>6, dd = ccA&63;
      #pragma unroll
      for (int i=0;i<4;i++){
        const int rb = row0 + wr*64 + i*16 + lk*4;
        u32 m01 = pack2bf(acc[i][jj][0]+bias, acc[i][jj][1]+bias);
        u32 m23 = pack2bf(acc[i][jj][2]+bias, acc[i][jj][3]+bias);
        u32 oa = __shfl_xor(m01,1);
        u32 ob = __shfl_xor(m23,1);
        u32 wA = even ? ((m01 & 0xffffu) | ((oa & 0xffffu)<<16))
                      : ((ob  & 0xffffu) | ((m23 & 0xffffu)<<16));
        u32 wB = even ? ((m01 >> 16) | (oa & 0xffff0000u))
                      : ((ob  >> 16) | (m23 & 0xffff0000u));
        const int rA = rb + (even ? 0 : 2);
        const int rB = rA + 1;
        if (sel==3){
          if (rA < n) dst32[(size_t)rA*128 + (ccA>>1)] = wA;
          if (rB < n) dst32[(size_t)rB*128 + (ccA>>1)] = wB;
        } else {
          if (rA < n) dst32[(((size_t)hh*n + rA)<<5) + (dd>>1)] = wA;
          if (rB < n) dst32[(((size_t)hh*n + rB)<<5) + (dd>>1)] = wB;
        }
      }
    }
  }
}

// ---------------- V column sums (for EPS correction) ----------------
__global__ void k_vcs(const u16* __restrict__ Vb, float* __restrict__ vcs, int n){
  const int h = blockIdx.y, tid = threadIdx.x;
  const int d = tid&63, seg = tid>>6;
  float s = 0.f;
  for (int node = blockIdx.x*4 + seg; node < n; node += 256)
    s += bf2f(Vb[(((size_t)h*n + node)<<6) + d]);
  __shared__ float sm[4][64];
  sm[seg][d] = s; __syncthreads();
  if (tid < 64){
    float t2 = sm[0][tid]+sm[1][tid]+sm[2][tid]+sm[3][tid];
    atomicAdd(vcs + h*64 + tid, t2);
  }
}

// ---------------- K3: single-pass kp -> ksum0/ctx0 partials + global dash max ----------------
__global__ __launch_bounds__(256) void k_ctx(
    const u16* __restrict__ Kb, const u16* __restrict__ Vb,
    const u16* __restrict__ projp,
    float* __restrict__ ctxp, float* __restrict__ ksump,
    u32* __restrict__ kmaxg, int n)
{
  __shared__ u32 kpT[288*32];     // kp^T [m][node-word], XOR-swizzled
  __shared__ u16 Vt[64][72];      // V^T tile [d][node]
  __shared__ float redk[4][288];
  const int tid = threadIdx.x;
  const int w = tid>>6, l = tid&63;
  const int bb = blockIdx.x;
  const int h = blockIdx.y;
  const int lm = l&15, lk = l>>4;
  f32x4 cacc[18] = {};
  float ksa[18] = {};
  float mreg = -3.0e38f;
  const int ntile = (n+63)>>6;
  #pragma unroll 1
  for (int t=bb; t<ntile; t+=NB){
    const int n0 = t*64;
    __syncthreads();
    #pragma unroll
    for (int q=0;q<2;q++){
      int e8 = tid + q*256;
      int nn = e8>>3, d0 = (e8&7)*8;
      uint4 rv = make_uint4(0,0,0,0);
      if (n0+nn < n) rv = *(const uint4*)(Vb + (((size_t)h*n + n0+nn)<<6) + d0);
      const u16* pv = (const u16*)&rv;
      #pragma unroll
      for (int s=0;s<8;s++) Vt[d0+s][nn] = pv[s];
    }
    int rr = n0 + w*16 + lm; if (rr > n-1) rr = n-1;
    const u16* Kbase = Kb + (((size_t)h*n + rr)<<6);
    bf16x8 af0 = *(const bf16x8*)(Kbase + lk*8);
    bf16x8 af1 = *(const bf16x8*)(Kbase + 32 + lk*8);
    float dg = 0.f;
    #pragma unroll
    for (int i2=0;i2<8;i2++){
      float a = bf2f(((const u16*)&af0)[i2]);
      float b = bf2f(((const u16*)&af1)[i2]);
      dg += a*a + b*b;
    }
    dg += __shfl_xor(dg,16); dg += __shfl_xor(dg,32);
    dg *= 0.0625f;
    float dgr[4];
    #pragma unroll
    for (int j=0;j<4;j++) dgr[j] = __shfl(dg, lk*4+j, 16);
    #pragma unroll
    for (int mt=0; mt<18; ++mt){
      bf16x8 b0 = *(const bf16x8*)(projp + (size_t)(mt*16+lm)*64 + lk*8);
      bf16x8 b1 = *(const bf16x8*)(projp + (size_t)(mt*16+lm)*64 + 32 + lk*8);
      f32x4 D = {0,0,0,0};
      D = MFMA16(af0, b0, D);
      D = MFMA16(af1, b1, D);
      const int m = mt*16 + lm;
      const bool vm = m < MF;
      float colsum = 0.f;
      u32 pk0 = 0, pk1 = 0;
      #pragma unroll
      for (int j=0;j<4;j++){
        float ddash = DN * D[j];
        float kp = 0.f;
        if (vm && (n0 + w*16 + lk*4 + j) < n){
          kp = RATIO * __expf(ddash - dgr[j]);
          mreg = fmaxf(mreg, ddash);
          colsum += kp;
        }
        if (j<2) pk0 |= ((u32)f2bf(kp)) << (16*j);
        else     pk1 |= ((u32)f2bf(kp)) << (16*(j-2));
      }
      const int wn0 = w*8 + lk*2;
      *(uint2*)&kpT[m*32 + (wn0 ^ ((m&7)<<2))] = make_uint2(pk0, pk1);
      colsum += __shfl_xor(colsum,16); colsum += __shfl_xor(colsum,32);
      ksa[mt] += colsum;
    }
    __syncthreads();
    #pragma unroll
    for (int mt=0; mt<18; ++mt){
      const int m = mt*16 + lm;
      #pragma unroll
      for (int ks=0;ks<2;++ks){
        bf16x8 a = *(const bf16x8*)&kpT[m*32 + ((ks*16 + lk*4) ^ ((m&7)<<2))];
        bf16x8 bv = *(const bf16x8*)&Vt[w*16+lm][ks*32 + lk*8];
        cacc[mt] = MFMA16(a, bv, cacc[mt]);
      }
    }
  }
  float* cp = ctxp + ((size_t)(h*NB + bb))*MP*64;
  #pragma unroll
  for (int mt=0;mt<18;++mt){
    #pragma unroll
    for (int j=0;j<4;j++){
      int m = mt*16 + lk*4 + j;
      cp[(size_t)m*64 + w*16 + lm] = cacc[mt][j];
    }
  }
  if (l < 16){
    #pragma unroll
    for (int mt=0;mt<18;++mt) redk[w][mt*16+lm] = ksa[mt];
  }
  __shared__ float redm[4];
  float mr = mreg;
  #pragma unroll
  for (int s=1;s<64;s<<=1) mr = fmaxf(mr, __shfl_xor(mr, s));
  if (l==0) redm[w] = mr;
  __syncthreads();
  for (int m2=tid; m2<MP; m2+=256){
    float s = redk[0][m2]+redk[1][m2]+redk[2][m2]+redk[3][m2];
    ksump[((size_t)(h*NB+bb))*MP + m2] = s;
  }
  if (tid==0){
    float bm = fmaxf(fmaxf(redm[0],redm[1]), fmaxf(redm[2],redm[3]));
    u32 b = __float_as_uint(bm);
    u32 enc = (b & 0x80000000u) ? ~b : (b | 0x80000000u);
    atomicMax(kmaxg + h, enc);
  }
}

// ---------------- K3b: reduce partials + apply max/EPS correction ----------------
__global__ void k_reduce(const float* __restrict__ ctxp, const float* __restrict__ ksump,
                         const u32* __restrict__ kmaxg, const float* __restrict__ vcs,
                         u16* __restrict__ ctxT, float* __restrict__ ksum, int n)
{
  const int T1 = NH*MP*64;
  int idx = blockIdx.x*256 + threadIdx.x;
  if (idx < T1){
    int h = idx/(MP*64), r = idx - h*MP*64, m = r>>6, d = r&63;
    u32 ee = kmaxg[h]; u32 b = (ee & 0x80000000u) ? (ee ^ 0x80000000u) : ~ee;
    float sc = __expf(-__uint_as_float(b));
    float s = 0.f;
    for (int bb=0; bb<NB; ++bb) s += ctxp[(((size_t)(h*NB+bb))*MP + m)*64 + d];
    float val = (m < MF) ? (sc*s + REPS*vcs[h*64 + d]) : 0.f;
    ctxT[((size_t)h*64 + d)*MP + m] = f2bf(val);
  } else if (idx < T1 + NH*MP){
    int k2 = idx - T1, h = k2/MP, m = k2 - h*MP;
    u32 ee = kmaxg[h]; u32 b = (ee & 0x80000000u) ? (ee ^ 0x80000000u) : ~ee;
    float sc = __expf(-__uint_as_float(b));
    float s = 0.f;
    for (int bb=0; bb<NB; ++bb) s += ksump[((size_t)(h*NB+bb))*MP + m];
    ksum[h*MP + m] = (m < MF) ? (sc*s + REPS*(float)n) : 0.f;
  }
}

// ---------------- K4: query path (MFMA, proj staged in LDS, grid-stride tiles) ----------------
__global__ __launch_bounds__(256) void k_qattn(
    const u16* __restrict__ Qb, const u16* __restrict__ projp,
    const u16* __restrict__ ctxT, const float* __restrict__ ksum,
    u16* __restrict__ trans, int n)
{
  __shared__ u32 pj[288*32];              // swizzled proj (36864 B)
  __shared__ u16 qp_lds[4][16][168];      // per-wave qp half (21504 B)
  const int tid = threadIdx.x;
  const int w = tid>>6, l = tid&63;
  const int h = blockIdx.y;
  const int lm = l&15, lk = l>>4;
  #pragma unroll
  for (int q=0; q<9; ++q){
    int cix = q*256 + tid;
    int row = cix>>3, c4 = (cix&7)*4;
    uint4 v = *(const uint4*)(projp + row*64 + c4*2);
    *(uint4*)&pj[row*32 + (c4 ^ ((row&7)<<2))] = v;
  }
  float ksm[18];
  #pragma unroll
  for (int mt=0;mt<18;++mt) ksm[mt] = ksum[h*MP + mt*16 + lm];
  __syncthreads();
  const int ntile = (n+63)>>6;
  #pragma unroll 1
  for (int t = blockIdx.x; t < ntile; t += NBQ){
    const int nb = t*64 + w*16;
    int rr = nb + lm; if (rr > n-1) rr = n-1;
    const u16* Qbase = Qb + (((size_t)h*n + rr)<<6);
    bf16x8 af0 = *(const bf16x8*)(Qbase + lk*8);
    bf16x8 af1 = *(const bf16x8*)(Qbase + 32 + lk*8);
    float dg = 0.f;
    #pragma unroll
    for (int i2=0;i2<8;i2++){
      float a = bf2f(((const u16*)&af0)[i2]);
      float b = bf2f(((const u16*)&af1)[i2]);
      dg += a*a + b*b;
    }
    dg += __shfl_xor(dg,16); dg += __shfl_xor(dg,32);
    dg *= 0.0625f;
    float dgr[4];
    #pragma unroll
    for (int j=0;j<4;j++) dgr[j] = __shfl(dg, lk*4+j, 16);
    f32x4 D[18];
    #pragma unroll
    for (int mt=0;mt<18;++mt){
      const int m = mt*16 + lm;
      bf16x8 b0 = *(const bf16x8*)&pj[m*32 + ((lk*4) ^ ((m&7)<<2))];
      bf16x8 b1 = *(const bf16x8*)&pj[m*32 + ((16 + lk*4) ^ ((m&7)<<2))];
      f32x4 z = {0,0,0,0};
      z = MFMA16(af0, b0, z);
      z = MFMA16(af1, b1, z);
      D[mt] = z;
    }
    float rmax[4] = {-3.0e38f,-3.0e38f,-3.0e38f,-3.0e38f};
    #pragma unroll
    for (int mt=0;mt<17;++mt){
      const bool vm = (mt<16) || (lm<10);
      #pragma unroll
      for (int j=0;j<4;j++){
        float dd = DN*D[mt][j];
        if (vm) rmax[j] = fmaxf(rmax[j], dd);
      }
    }
    #pragma unroll
    for (int j=0;j<4;j++){
      #pragma unroll
      for (int s=1;s<16;s<<=1) rmax[j] = fmaxf(rmax[j], __shfl_xor(rmax[j], s));
    }
    float den[4] = {0,0,0,0};
    f32x4 o[4] = {{0,0,0,0},{0,0,0,0},{0,0,0,0},{0,0,0,0}};
    #pragma unroll
    for (int mt=0;mt<10;++mt){
      #pragma unroll
      for (int j=0;j<4;j++){
        float qp = RATIO*(__expf(DN*D[mt][j] - dgr[j] - rmax[j]) + EPSRF);
        den[j] += qp * ksm[mt];
        qp_lds[w][lk*4+j][mt*16+lm] = f2bf(qp);
      }
    }
    #pragma unroll
    for (int ks=0;ks<5;++ks){
      bf16x8 av = *(const bf16x8*)&qp_lds[w][lm][ks*32 + lk*8];
      #pragma unroll
      for (int dt=0;dt<4;++dt){
        bf16x8 bv = *(const bf16x8*)(ctxT + (size_t)(h*64 + dt*16 + lm)*MP + ks*32 + lk*8);
        o[dt] = MFMA16(av, bv, o[dt]);
      }
    }
    #pragma unroll
    for (int mt=10;mt<18;++mt){
      #pragma unroll
      for (int j=0;j<4;j++){
        float qp = RATIO*(__expf(DN*D[mt][j] - dgr[j] - rmax[j]) + EPSRF);
        den[j] += qp * ksm[mt];
        qp_lds[w][lk*4+j][(mt-10)*16+lm] = f2bf(qp);
      }
    }
    #pragma unroll
    for (int ks=5;ks<9;++ks){
      bf16x8 av = *(const bf16x8*)&qp_lds[w][lm][(ks-5)*32 + lk*8];
      #pragma unroll
      for (int dt=0;dt<4;++dt){
        bf16x8 bv = *(const bf16x8*)(ctxT + (size_t)(h*64 + dt*16 + lm)*MP + ks*32 + lk*8);
        o[dt] = MFMA16(av, bv, o[dt]);
      }
    }
    #pragma unroll
    for (int j=0;j<4;j++){
      #pragma unroll
      for (int s=1;s<16;s<<=1) den[j] += __shfl_xor(den[j], s);
    }
    #pragma unroll
    for (int j=0;j<4;j++){
      const int node = nb + lk*4 + j;
      if (node < n){
        const float dv = 1.f/den[j];
        #pragma unroll
        for (int dt=0;dt<4;++dt)
          trans[(size_t)node*256 + h*64 + dt*16 + lm] = f2bf(o[dt][j]*dv);
      }
    }
  }
}

// ---------------- K5: cat -> elu -> lin2 -> elu (MFMA) ----------------
__global__ __launch_bounds__(256) void k_gnn2(
    const u16* __restrict__ G1, const u16* __restrict__ trans,
    const u16* __restrict__ l2wb, const float* __restrict__ l2b,
    u16* __restrict__ xb0, int n)
{
  __shared__ u32 cat[64*256];   // 64 nodes x 512 bf16, swizzled
  const int tid = threadIdx.x;
  const int w = tid>>6, l = tid&63;
  const int lm = l&15, lk = l>>4;
  const int n0 = blockIdx.x*64;
  #pragma unroll
  for (int src=0; src<2; ++src){
    const u16* S = src ? trans : G1;
    #pragma unroll
    for (int q=0;q<8;++q){
      int idx = q*256 + tid;
      int row = idx>>5, v8 = idx&31;
      int rr = n0+row; if (rr > n-1) rr = n-1;
      uint4 raw = *(const uint4*)(S + (size_t)rr*256 + v8*8);
      const u16* p = (const u16*)&raw;
      u32 o2[4];
      #pragma unroll
      for (int t2=0;t2<4;++t2)
        o2[t2] = pack2bf(eluf(bf2f(p[t2*2])), eluf(bf2f(p[t2*2+1])));
      int word = (v8*4 + src*128) ^ ((row&7)<<2);
      *(uint4*)&cat[row*256 + word] = *(uint4*)o2;
    }
  }
  __syncthreads();
  f32x4 acc[2] = {{0,0,0,0},{0,0,0,0}};
  const int rowl = w*16 + lm;
  #pragma unroll 4
  for (int kt=0; kt<16; ++kt){
    bf16x8 a = *(const bf16x8*)&cat[rowl*256 + ((kt*16 + lk*4) ^ ((rowl&7)<<2))];
    #pragma unroll
    for (int jj=0;jj<2;++jj){
      bf16x8 b = *(const bf16x8*)(l2wb + (size_t)(jj*16+lm)*512 + kt*32 + lk*8);
      acc[jj] = MFMA16(a, b, acc[jj]);
    }
  }
  #pragma unroll
  for (int jj=0;jj<2;++jj){
    const int o = jj*16 + lm;
    const float bias = l2b[o];
    #pragma unroll
    for (int jr=0;jr<4;++jr){
      const int node = n0 + w*16 + lk*4 + jr;
      if (node < n)
        xb0[(size_t)node*32 + o] = f2bf(eluf(acc[jj][jr] + bias));
    }
  }
}

// ---------------- edge layout detect ----------------
__global__ void k_edgemode(const int* __restrict__ ei, int* __restrict__ mode){
  __shared__ int any;
  if (threadIdx.x==0) any = 0;
  __syncthreads();
  if (ei[threadIdx.x*2+1] != 0) any = 1;
  __syncthreads();
  if (threadIdx.x==0) *mode = any;
}
__device__ __forceinline__ int edge_at(const int* ei, int mode, size_t idx){
  if (mode) return ei[idx];
  return (int)((const long long*)ei)[idx];
}

// ---------------- CSR build ----------------
__global__ void k_hist(const int* __restrict__ ei, const int* __restrict__ mode,
                       u32* __restrict__ deg, int e){
  const int md = *mode;
  for (size_t i = (size_t)blockIdx.x*blockDim.x + threadIdx.x; i < (size_t)e; i += (size_t)gridDim.x*blockDim.x)
    atomicAdd(&deg[edge_at(ei, md, (size_t)e + i)], 1u);
}
__global__ void k_dis(const u32* __restrict__ deg, float* __restrict__ dis, int n){
  int i = blockIdx.x*256 + threadIdx.x;
  if (i<n) dis[i] = rsqrtf((float)(deg[i] + 1u));
}
// ---------------- parallel prefix scan (3 kernels) ----------------
__global__ __launch_bounds__(256) void k_bsum(const u32* __restrict__ deg,
                                              u32* __restrict__ bsum, int n){
  __shared__ u32 red[4];
  const int tid = threadIdx.x, lane = tid&63, wv = tid>>6;
  const int base = blockIdx.x*1024;
  u32 s = 0;
  #pragma unroll
  for (int q=0;q<4;++q){
    int i = base + q*256 + tid;
    if (i<n) s += deg[i];
  }
  #pragma unroll
  for (int off=1; off<64; off<<=1) s += __shfl_xor(s, off, 64);
  if (lane==0) red[wv] = s;
  __syncthreads();
  if (tid==0) bsum[blockIdx.x] = red[0]+red[1]+red[2]+red[3];
}
__global__ __launch_bounds__(1024) void k_bscan(u32* __restrict__ bsum,
                                                u32* __restrict__ rowp, int nblk){
  __shared__ u32 wsum[16];
  __shared__ u32 carry;
  const int tid = threadIdx.x, lane = tid&63, wv = tid>>6;
  if (tid==0){ carry = 0u; rowp[0] = 0u; }
  __syncthreads();
  for (int base=0; base<nblk; base+=1024){
    int i = base + tid;
    u32 v = (i<nblk)? bsum[i] : 0u;
    u32 s = v;
    #pragma unroll
    for (int off=1; off<64; off<<=1){
      u32 t = __shfl_up(s, off, 64);
      if (lane >= off) s += t;
    }
    if (lane==63) wsum[wv] = s;
    __syncthreads();
    if (wv==0){
      u32 ws = (lane<16)? wsum[lane] : 0u;
      #pragma unroll
      for (int off=1; off<16; off<<=1){
        u32 t = __shfl_up(ws, off, 64);
        if (lane >= off) ws += t;
      }
      if (lane<16) wsum[lane] = ws;
    }
    __syncthreads();
    if (i<nblk) bsum[i] = carry + (wv ? wsum[wv-1] : 0u) + s - v;  // exclusive
    __syncthreads();
    if (tid==0) carry += wsum[15];
    __syncthreads();
  }
}
__global__ __launch_bounds__(1024) void k_scan2(const u32* __restrict__ deg,
                                                const u32* __restrict__ bsum,
                                                u32* __restrict__ rowp, int n){
  __shared__ u32 wsum[16];
  const int tid = threadIdx.x, lane = tid&63, wv = tid>>6;
  const int i = blockIdx.x*1024 + tid;
  u32 v = (i<n)? deg[i] : 0u;
  u32 s = v;
  #pragma unroll
  for (int off=1; off<64; off<<=1){
    u32 t = __shfl_up(s, off, 64);
    if (lane >= off) s += t;
  }
  if (lane==63) wsum[wv] = s;
  __syncthreads();
  if (wv==0){
    u32 ws = (lane<16)? wsum[lane] : 0u;
    #pragma unroll
    for (int off=1; off<16; off<<=1){
      u32 t = __shfl_up(ws, off, 64);
      if (lane >= off) ws += t;
    }
    if (lane<16) wsum[lane] = ws;
  }
  __syncthreads();
  if (i<n) rowp[i+1] = bsum[blockIdx.x] + (wv ? wsum[wv-1] : 0u) + s;
}
__global__ void k_copy(const u32* __restrict__ a, u32* __restrict__ b, int n){
  int i = blockIdx.x*256 + threadIdx.x; if (i<n) b[i]=a[i];
}
__global__ void k_fill(const int* __restrict__ ei, const int* __restrict__ mode,
                       const float* __restrict__ dis,
                       u32* __restrict__ cur, uint2* __restrict__ cw, int e){
  const int md = *mode;
  for (size_t i = (size_t)blockIdx.x*blockDim.x + threadIdx.x; i < (size_t)e; i += (size_t)gridDim.x*blockDim.x){
    int s = edge_at(ei, md, i);
    int t = edge_at(ei, md, (size_t)e + i);
    u32 pos = atomicAdd(&cur[t], 1u);
    cw[pos] = make_uint2((u32)s, __float_as_uint(dis[s]*dis[t]));
  }
}

// ---------------- APPNP iteration (8 lanes/node, uint2 gathers, 4-unroll) ----------------
__global__ __launch_bounds__(256) void k_appnp(
    const u16* __restrict__ xin, const u16* __restrict__ hb16,
    u16* __restrict__ xout, const u32* __restrict__ rowp,
    const uint2* __restrict__ cw, const float* __restrict__ dis, int n)
{
  const int g = threadIdx.x>>3, j4 = threadIdx.x&7;
  const int node = blockIdx.x*32 + g;
  if (node >= n) return;
  const uint2* x64 = (const uint2*)xin;
  float d0 = dis[node];
  float dd = d0*d0;
  uint2 xv = x64[((size_t)node<<3) + j4];
  float a0 = dd*bf2f((u16)xv.x), a1 = dd*bf2f((u16)(xv.x>>16));
  float a2 = dd*bf2f((u16)xv.y), a3 = dd*bf2f((u16)(xv.y>>16));
  u32 r0 = rowp[node], r1 = rowp[node+1];
  u32 k = r0;
  for (; k+4 <= r1; k += 4){
    uint2 e0 = cw[k], e1 = cw[k+1], e2 = cw[k+2], e3 = cw[k+3];
    uint2 v0 = x64[((size_t)e0.x<<3)+j4], v1 = x64[((size_t)e1.x<<3)+j4];
    uint2 v2 = x64[((size_t)e2.x<<3)+j4], v3 = x64[((size_t)e3.x<<3)+j4];
    float w0=__uint_as_float(e0.y), w1=__uint_as_float(e1.y);
    float w2=__uint_as_float(e2.y), w3=__uint_as_float(e3.y);
    a0 += w0*bf2f((u16)v0.x) + w1*bf2f((u16)v1.x) + w2*bf2f((u16)v2.x) + w3*bf2f((u16)v3.x);
    a1 += w0*bf2f((u16)(v0.x>>16)) + w1*bf2f((u16)(v1.x>>16)) + w2*bf2f((u16)(v2.x>>16)) + w3*bf2f((u16)(v3.x>>16));
    a2 += w0*bf2f((u16)v0.y) + w1*bf2f((u16)v1.y) + w2*bf2f((u16)v2.y) + w3*bf2f((u16)v3.y);
    a3 += w0*bf2f((u16)(v0.y>>16)) + w1*bf2f((u16)(v1.y>>16)) + w2*bf2f((u16)(v2.y>>16)) + w3*bf2f((u16)(v3.y>>16));
  }
  for (; k < r1; ++k){
    uint2 e = cw[k];
    uint2 v = x64[((size_t)e.x<<3)+j4];
    float wgt = __uint_as_float(e.y);
    a0 += wgt*bf2f((u16)v.x);
    a1 += wgt*bf2f((u16)(v.x>>16));
    a2 += wgt*bf2f((u16)v.y);
    a3 += wgt*bf2f((u16)(v.y>>16));
  }
  uint2 hv = ((const uint2*)hb16)[((size_t)node<<3) + j4];
  uint2 o;
  o.x = pack2bf(0.9f*a0 + 0.1f*bf2f((u16)hv.x), 0.9f*a1 + 0.1f*bf2f((u16)(hv.x>>16)));
  o.y = pack2bf(0.9f*a2 + 0.1f*bf2f((u16)hv.y), 0.9f*a3 + 0.1f*bf2f((u16)(hv.y>>16)));
  ((uint2*)xout)[((size_t)node<<3) + j4] = o;
}

// ---------------- final APPNP iteration fused with log_softmax + raw write ----------------
__global__ __launch_bounds__(256) void k_appnp_lsm(
    const u16* __restrict__ xin, const u16* __restrict__ hb16,
    float* __restrict__ out, const u32* __restrict__ rowp,
    const uint2* __restrict__ cw, const float* __restrict__ dis, int n)
{
  const int g = threadIdx.x>>3, j4 = threadIdx.x&7;
  const int node = blockIdx.x*32 + g;
  if (node >= n) return;
  const uint2* x64 = (const uint2*)xin;
  float d0 = dis[node];
  float dd = d0*d0;
  uint2 xv = x64[((size_t)node<<3) + j4];
  float a0 = dd*bf2f((u16)xv.x), a1 = dd*bf2f((u16)(xv.x>>16));
  float a2 = dd*bf2f((u16)xv.y), a3 = dd*bf2f((u16)(xv.y>>16));
  u32 r0 = rowp[node], r1 = rowp[node+1];
  u32 k = r0;
  for (; k+4 <= r1; k += 4){
    uint2 e0 = cw[k], e1 = cw[k+1], e2 = cw[k+2], e3 = cw[k+3];
    uint2 v0 = x64[((size_t)e0.x<<3)+j4], v1 = x64[((size_t)e1.x<<3)+j4];
    uint2 v2 = x64[((size_t)e2.x<<3)+j4], v3 = x64[((size_t)e3.x<<3)+j4];
    float w0=__uint_as_float(e0.y), w1=__uint_as_float(e1.y);
    float w2=__uint_as_float(e2.y), w3=__uint_as_float(e3.y);
    a0 += w0*bf2f((u16)v0.x) + w1*bf2f((u16)v1.x) + w2*bf2f((u16)v2.x) + w3*bf2f((u16)v3.x);
    a1 += w0*bf2f((u16)(v0.x>>16)) + w1*bf2f((u16)(v1.x>>16)) + w2*bf2f((u16)(v2.x>>16)) + w3*bf2f((u16)(v3.x>>16));
    a2 += w0*bf2f((u16)v0.y) + w1*bf2f((u16)v1.y) + w2*bf2f((u16)v2.y) + w3*bf2f((u16)v3.y);
    a3 += w0*bf2f((u16)(v0.y>>16)) + w1*bf2f((u16)(v1.y>>16)) + w2*bf2f((u16)(v2.y>>16)) + w3*bf2f((u16)(v3.y>>16));
  }
  for (; k < r1; ++k){
    uint2 e = cw[k];
    uint2 v = x64[((size_t)e.x<<3)+j4];
    float wgt = __uint_as_float(e.y);
    a0 += wgt*bf2f((u16)v.x);
    a1 += wgt*bf2f((u16)(v.x>>16));
    a2 += wgt*bf2f((u16)v.y);
    a3 += wgt*bf2f((u16)(v.y>>16));
  }
  uint2 hv = ((const uint2*)hb16)[((size_t)node<<3) + j4];
  float v0 = 0.9f*a0 + 0.1f*bf2f((u16)hv.x);
  float v1 = 0.9f*a1 + 0.1f*bf2f((u16)(hv.x>>16));
  float v2 = 0.9f*a2 + 0.1f*bf2f((u16)hv.y);
  float v3 = 0.9f*a3 + 0.1f*bf2f((u16)(hv.y>>16));
  float m = fmaxf(fmaxf(v0,v1), fmaxf(v2,v3));
  #pragma unroll
  for (int o2=1;o2<8;o2<<=1) m = fmaxf(m, __shfl_xor(m, o2, 8));
  float s = __expf(v0-m)+__expf(v1-m)+__expf(v2-m)+__expf(v3-m);
  #pragma unroll
  for (int o2=1;o2<8;o2<<=1) s += __shfl_xor(s, o2, 8);
  float ls = m + logf(s);
  float4 lsv = make_float4(v0-ls, v1-ls, v2-ls, v3-ls);
  *(float4*)(out + (size_t)node*32 + j4*4) = lsv;
  float4 raw = make_float4(v0, v1, v2, v3);
  *(float4*)(out + (size_t)n*32 + (size_t)node*32 + j4*4) = raw;
}

extern "C" void kernel_launch(void* const* d_in, const int* in_sizes, int n_in,
                              void* d_out, int out_size, void* d_ws, size_t ws_size,
                              hipStream_t stream)
{
  const float* x   = (const float*)d_in[0];
  const int*   ei  = (const int*)  d_in[1];
  const float* l1w = (const float*)d_in[2];
  const float* l1b = (const float*)d_in[3];
  const float* l2w = (const float*)d_in[4];
  const float* l2b = (const float*)d_in[5];
  const float* qw  = (const float*)d_in[6];
  const float* qb  = (const float*)d_in[7];
  const float* kw  = (const float*)d_in[8];
  const float* kb  = (const float*)d_in[9];
  const float* vw  = (const float*)d_in[10];
  const float* vb  = (const float*)d_in[11];
  const float* proj= (const float*)d_in[12];
  const int n = in_sizes[0] / 256;
  const int e = in_sizes[1] / 2;

  char* ws = (char*)d_ws;
  auto au = [](size_t v){ return (v + 255) & ~(size_t)255; };
  const size_t bQ = (size_t)n * 512;
  const size_t oQ = 0;
  const size_t oK = au(oQ + bQ);
  const size_t oV = au(oK + bQ);
  const size_t oG1 = au(oV + bQ);
  const size_t oCtxp = au(oG1 + bQ);
  const size_t bCtxp = (size_t)NH*NB*MP*64*4;
  const size_t oKsump = au(oCtxp + bCtxp);
  const size_t bKsump = (size_t)NH*NB*MP*4;
  const size_t oCtxT = au(oKsump + bKsump);
  const size_t oKsum = au(oCtxT + (size_t)NH*64*MP*2);
  const size_t oKmax = au(oKsum + (size_t)NH*MP*4);
  const size_t oVcs  = oKmax + 256;
  const size_t oMode = oVcs + 1024;
  const size_t oL2wb = au(oMode + 256);
  const size_t oWb   = au(oL2wb + 32768);
  const size_t oProjp= au(oWb + (size_t)1024*256*2);
  const size_t oTrans = oK;
  const size_t oG2 = oQ;
  const size_t oXb0 = au(oG2 + (size_t)n*32*4);
  const size_t oXbA = au(oXb0 + (size_t)n*32*2);
  const size_t oXbB = au(oXbA + (size_t)n*32*2);
  const size_t oDeg = au(oXbB + (size_t)n*32*2);
  const size_t oDis = au(oDeg + (size_t)n*4);
  const size_t oRowp= au(oDis + (size_t)n*4);
  const size_t oCur = au(oRowp + (size_t)(n+1)*4);
  const size_t oBsum= au(oCur + (size_t)(n+1)*4);
  const size_t oCw  = oV;
  (void)ws_size; (void)n_in; (void)out_size;

  u16* Q  = (u16*)(ws + oQ);
  u16* Kb = (u16*)(ws + oK);
  u16* Vb = (u16*)(ws + oV);
  u16* G1 = (u16*)(ws + oG1);
  float* ctxp = (float*)(ws + oCtxp);
  float* ksump= (float*)(ws + oKsump);
  u16*  ctxT  = (u16*)(ws + oCtxT);
  float* ksum = (float*)(ws + oKsum);
  u32*  kmax  = (u32*)(ws + oKmax);
  float* Vcs  = (float*)(ws + oVcs);
  int*  mode  = (int*)(ws + oMode);
  u16*  l2wb  = (u16*)(ws + oL2wb);
  u16*  Wb    = (u16*)(ws + oWb);
  u16*  projp = (u16*)(ws + oProjp);
  u16* trans  = (u16*)(ws + oTrans);
  u16* xb0    = (u16*)(ws + oXb0);
  u16* xbA    = (u16*)(ws + oXbA);
  u16* xbB    = (u16*)(ws + oXbB);
  u32* deg    = (u32*)(ws + oDeg);
  float* dis  = (float*)(ws + oDis);
  u32* rowp   = (u32*)(ws + oRowp);
  u32* cur    = (u32*)(ws + oCur);
  u32* bsum   = (u32*)(ws + oBsum);
  uint2* cw   = (uint2*)(ws + oCw);

  k_cvtw<<<1024,256,0,stream>>>(qw,kw,vw,l1w,l2w,proj,Wb,projp,l2wb);
  k_proj<<<(n+127)/128,512,0,stream>>>(x,Wb,qb,kb,vb,l1b,Q,Kb,Vb,G1,n);
  hipMemsetAsync(ws + oKmax, 0, 16, stream);
  hipMemsetAsync(ws + oVcs, 0, 1024, stream);
  k_vcs<<<dim3(64,4),256,0,stream>>>(Vb,Vcs,n);
  k_ctx<<<dim3(NB,NH),256,0,stream>>>(Kb,Vb,projp,ctxp,ksump,kmax,n);
  {
    int tot = NH*MP*64 + NH*MP;
    k_reduce<<<(tot+255)/256,256,0,stream>>>(ctxp,ksump,kmax,Vcs,ctxT,ksum,n);
  }
  k_qattn<<<dim3(NBQ,4),256,0,stream>>>(Q,projp,ctxT,ksum,trans,n);
  k_gnn2<<<(n+63)/64,256,0,stream>>>(G1,trans,l2wb,l2b,xb0,n);
  // ---- APPNP ----
  k_edgemode<<<1,256,0,stream>>>(ei,mode);
  hipMemsetAsync(ws + oDeg, 0, (size_t)n*4, stream);
  k_hist<<<2048,256,0,stream>>>(ei,mode,deg,e);
  k_dis<<<(n+255)/256,256,0,stream>>>(deg,dis,n);
  {
    const int nblk = (n+1023)/1024;
    k_bsum<<<nblk,256,0,stream>>>(deg,bsum,n);
    k_bscan<<<1,1024,0,stream>>>(bsum,rowp,nblk);
    k_scan2<<<nblk,1024,0,stream>>>(deg,bsum,rowp,n);
  }
  k_copy<<<(n+255)/256,256,0,stream>>>(rowp,cur,n);
  k_fill<<<2048,256,0,stream>>>(ei,mode,dis,cur,cw,e);
  const u16* curx = xb0;
  u16* bufs[2] = {xbA, xbB};
  for (int it=0; it<9; ++it){
    u16* nxt = bufs[it&1];
    k_appnp<<<(n+31)/32,256,0,stream>>>(curx,xb0,nxt,rowp,cw,dis,n);
    curx = nxt;
  }
  k_appnp_lsm<<<(n+31)/32,256,0,stream>>>(curx,xb0,(float*)d_out,rowp,cw,dis,n);
}

// Round 12
// 1397.730 us; speedup vs baseline: 1.1264x; 1.0046x over previous
//
#include <hip/hip_runtime.h>
#include <hip/hip_fp16.h>

#define NH 4
#define HD 64
#define MF 266
#define MP 288           // MF padded to multiple of 32 for MFMA K-steps
#define NB 192           // k_ctx partial blocks
#define NBQ 128          // k_qattn blocks per head (grid-stride)
#define DN 0.35355339059327373f
#define RATIO 0.06131393394849658f
#define EPSRF 1e-4f
#define REPS (RATIO*EPSRF)

typedef unsigned short u16;
typedef unsigned int u32;
typedef __attribute__((ext_vector_type(8))) short bf16x8;
typedef __attribute__((ext_vector_type(4))) float f32x4;
#define MFMA16(a,b,c) __builtin_amdgcn_mfma_f32_16x16x32_bf16(a,b,c,0,0,0)

__device__ __forceinline__ float bf2f(u16 u){ return __uint_as_float(((u32)u)<<16); }
__device__ __forceinline__ u16 f2bf(float f){ u32 u = __float_as_uint(f); u += 0x7FFFu + ((u>>16)&1u); return (u16)(u>>16); }
__device__ __forceinline__ u32 pack2bf(float a, float b){ return ((u32)f2bf(b)<<16) | f2bf(a); }
__device__ __forceinline__ float eluf(float x){ return x>0.f ? x : (expf(x)-1.f); }

// ---------------- weight/proj conversion to bf16 ----------------
__global__ void k_cvtw(const float* __restrict__ qw, const float* __restrict__ kw,
                       const float* __restrict__ vw, const float* __restrict__ lw,
                       const float* __restrict__ l2w, const float* __restrict__ proj,
                       u16* __restrict__ Wb, u16* __restrict__ projp, u16* __restrict__ l2wb){
  int i = blockIdx.x*256 + threadIdx.x;
  if (i < 262144){
    int sec = i>>16, r = i&65535;
    const float* s = sec==0?qw : sec==1?kw : sec==2?vw : lw;
    Wb[i] = f2bf(s[r]);
  }
  if (i < MP*64){
    int r = i>>6, c = i&63;
    projp[i] = f2bf(r < MF ? proj[r*64 + c] : 0.f);
  }
  if (i < 32*512) l2wb[i] = f2bf(l2w[i]);
}

// ---------------- K1: fused projection GEMM (round-6 shape: 128-row X stage, 8 waves) ----------------
__global__ __launch_bounds__(512,4) void k_proj(
    const float* __restrict__ x, const u16* __restrict__ Wb,
    const float* __restrict__ qb, const float* __restrict__ kb,
    const float* __restrict__ vb, const float* __restrict__ lb,
    u16* __restrict__ Q, u16* __restrict__ K, u16* __restrict__ V,
    u16* __restrict__ G1, int n)
{
  __shared__ u32 Xs[128*128];   // [row][word 0..127], XOR-swizzled
  const int tid = threadIdx.x;
  const int w = tid>>6, l = tid&63;
  const int wr = w>>2, wc = w&3;
  const int lm = l&15, lk = l>>4;
  const int row0 = blockIdx.x*128;
  #pragma unroll 4
  for (int q=0;q<16;++q){
    int idx = q*512 + tid;          // 0..8191 float4s
    int r = idx>>6, c4 = idx&63;
    int rr = row0 + r; if (rr > n-1) rr = n-1;
    float4 v = *(const float4*)(x + (size_t)rr*256 + c4*4);
    int word = (c4*2) ^ ((r&7)<<2);
    *(uint2*)&Xs[r*128 + word] = make_uint2(pack2bf(v.x,v.y), pack2bf(v.z,v.w));
  }
  __syncthreads();
  #pragma unroll 1
  for (int ct=0; ct<8; ++ct){
    const int c0 = ct*128 + wc*32;
    f32x4 acc[4][2] = {};
    #pragma unroll 2
    for (int kt=0; kt<8; ++kt){
      bf16x8 Af[4], Bf[2];
      #pragma unroll
      for (int jj=0;jj<2;jj++)
        Bf[jj] = *(const bf16x8*)(Wb + (size_t)(c0 + jj*16 + lm)*256 + kt*32 + lk*8);
      #pragma unroll
      for (int i=0;i<4;i++){
        const int rl = wr*64 + i*16 + lm;
        Af[i] = *(const bf16x8*)&Xs[rl*128 + ((kt*16 + lk*4) ^ ((rl&7)<<2))];
      }
      #pragma unroll
      for (int i=0;i<4;i++)
        #pragma unroll
        for (int jj=0;jj<2;jj++)
          acc[i][jj] = MFMA16(Af[i], Bf[jj], acc[i][jj]);
    }
    const int sel = c0>>8;
    const float* bp = sel==0?qb : sel==1?kb : sel==2?vb : lb;
    u16* d3 = sel==0?Q : sel==1?K : sel==2?V : G1;
    u32* dst32 = (u32*)d3;
    const bool even = (lm&1)==0;
    #pragma unroll
    for (int jj=0;jj<2;jj++){
      const int cc = (c0&255) + jj*16 + lm;
      const float bias = bp[cc];
      const int ccA = cc & ~1;
      const int hh = ccA>>6, dd = ccA&63;
      #pragma unroll
      for (int i=0;i<4;i++){
        const int rb = row0 + wr*64 + i*16 + lk*4;
        u32 m01 = pack2bf(acc[i][jj][0]+bias, acc[i][jj][1]+bias);
        u32 m23 = pack2bf(acc[i][jj][2]+bias, acc[i][jj][3]+bias);
        u32 oa = __shfl_xor(m01,1);
        u32 ob = __shfl_xor(m23,1);
        u32 wA = even ? ((m01 & 0xffffu) | ((oa & 0xffffu)<<16))
                      : ((ob  & 0xffffu) | ((m23 & 0xffffu)<<16));
        u32 wB = even ? ((m01 >> 16) | (oa & 0xffff0000u))
                      : ((ob  >> 16) | (m23 & 0xffff0000u));
        const int rA = rb + (even ? 0 : 2);
        const int rB = rA + 1;
        if (sel==3){
          if (rA < n) dst32[(size_t)rA*128 + (ccA>>1)] = wA;
          if (rB < n) dst32[(size_t)rB*128 + (ccA>>1)] = wB;
        } else {
          if (rA < n) dst32[(((size_t)hh*n + rA)<<5) + (dd>>1)] = wA;
          if (rB < n) dst32[(((size_t)hh*n + rB)<<5) + (dd>>1)] = wB;
        }
      }
    }
  }
}

// ---------------- V column sums (for EPS correction) ----------------
__global__ void k_vcs(const u16* __restrict__ Vb, float* __restrict__ vcs, int n){
  const int h = blockIdx.y, tid = threadIdx.x;
  const int d = tid&63, seg = tid>>6;
  float s = 0.f;
  for (int node = blockIdx.x*4 + seg; node < n; node += 256)
    s += bf2f(Vb[(((size_t)h*n + node)<<6) + d]);
  __shared__ float sm[4][64];
  sm[seg][d] = s; __syncthreads();
  if (tid < 64){
    float t2 = sm[0][tid]+sm[1][tid]+sm[2][tid]+sm[3][tid];
    atomicAdd(vcs + h*64 + tid, t2);
  }
}

// ---------------- K3: single-pass kp -> ksum0/ctx0 partials + global dash max ----------------
__global__ __launch_bounds__(256) void k_ctx(
    const u16* __restrict__ Kb, const u16* __restrict__ Vb,
    const u16* __restrict__ projp,
    float* __restrict__ ctxp, float* __restrict__ ksump,
    u32* __restrict__ kmaxg, int n)
{
  __shared__ u32 kpT[288*32];     // kp^T [m][node-word], XOR-swizzled
  __shared__ u16 Vt[64][72];      // V^T tile [d][node]
  __shared__ float redk[4][288];
  const int tid = threadIdx.x;
  const int w = tid>>6, l = tid&63;
  const int bb = blockIdx.x;
  const int h = blockIdx.y;
  const int lm = l&15, lk = l>>4;
  f32x4 cacc[18] = {};
  float ksa[18] = {};
  float mreg = -3.0e38f;
  const int ntile = (n+63)>>6;
  #pragma unroll 1
  for (int t=bb; t<ntile; t+=NB){
    const int n0 = t*64;
    __syncthreads();
    #pragma unroll
    for (int q=0;q<2;q++){
      int e8 = tid + q*256;
      int nn = e8>>3, d0 = (e8&7)*8;
      uint4 rv = make_uint4(0,0,0,0);
      if (n0+nn < n) rv = *(const uint4*)(Vb + (((size_t)h*n + n0+nn)<<6) + d0);
      const u16* pv = (const u16*)&rv;
      #pragma unroll
      for (int s=0;s<8;s++) Vt[d0+s][nn] = pv[s];
    }
    int rr = n0 + w*16 + lm; if (rr > n-1) rr = n-1;
    const u16* Kbase = Kb + (((size_t)h*n + rr)<<6);
    bf16x8 af0 = *(const bf16x8*)(Kbase + lk*8);
    bf16x8 af1 = *(const bf16x8*)(Kbase + 32 + lk*8);
    float dg = 0.f;
    #pragma unroll
    for (int i2=0;i2<8;i2++){
      float a = bf2f(((const u16*)&af0)[i2]);
      float b = bf2f(((const u16*)&af1)[i2]);
      dg += a*a + b*b;
    }
    dg += __shfl_xor(dg,16); dg += __shfl_xor(dg,32);
    dg *= 0.0625f;
    float dgr[4];
    #pragma unroll
    for (int j=0;j<4;j++) dgr[j] = __shfl(dg, lk*4+j, 16);
    #pragma unroll
    for (int mt=0; mt<18; ++mt){
      bf16x8 b0 = *(const bf16x8*)(projp + (size_t)(mt*16+lm)*64 + lk*8);
      bf16x8 b1 = *(const bf16x8*)(projp + (size_t)(mt*16+lm)*64 + 32 + lk*8);
      f32x4 D = {0,0,0,0};
      D = MFMA16(af0, b0, D);
      D = MFMA16(af1, b1, D);
      const int m = mt*16 + lm;
      const bool vm = m < MF;
      float colsum = 0.f;
      u32 pk0 = 0, pk1 = 0;
      #pragma unroll
      for (int j=0;j<4;j++){
        float ddash = DN * D[j];
        float kp = 0.f;
        if (vm && (n0 + w*16 + lk*4 + j) < n){
          kp = RATIO * __expf(ddash - dgr[j]);
          mreg = fmaxf(mreg, ddash);
          colsum += kp;
        }
        if (j<2) pk0 |= ((u32)f2bf(kp)) << (16*j);
        else     pk1 |= ((u32)f2bf(kp)) << (16*(j-2));
      }
      const int wn0 = w*8 + lk*2;
      *(uint2*)&kpT[m*32 + (wn0 ^ ((m&7)<<2))] = make_uint2(pk0, pk1);
      colsum += __shfl_xor(colsum,16); colsum += __shfl_xor(colsum,32);
      ksa[mt] += colsum;
    }
    __syncthreads();
    #pragma unroll
    for (int mt=0; mt<18; ++mt){
      const int m = mt*16 + lm;
      #pragma unroll
      for (int ks=0;ks<2;++ks){
        bf16x8 a = *(const bf16x8*)&kpT[m*32 + ((ks*16 + lk*4) ^ ((m&7)<<2))];
        bf16x8 bv = *(const bf16x8*)&Vt[w*16+lm][ks*32 + lk*8];
        cacc[mt] = MFMA16(a, bv, cacc[mt]);
      }
    }
  }
  float* cp = ctxp + ((size_t)(h*NB + bb))*MP*64;
  #pragma unroll
  for (int mt=0;mt<18;++mt){
    #pragma unroll
    for (int j=0;j<4;j++){
      int m = mt*16 + lk*4 + j;
      cp[(size_t)m*64 + w*16 + lm] = cacc[mt][j];
    }
  }
  if (l < 16){
    #pragma unroll
    for (int mt=0;mt<18;++mt) redk[w][mt*16+lm] = ksa[mt];
  }
  __shared__ float redm[4];
  float mr = mreg;
  #pragma unroll
  for (int s=1;s<64;s<<=1) mr = fmaxf(mr, __shfl_xor(mr, s));
  if (l==0) redm[w] = mr;
  __syncthreads();
  for (int m2=tid; m2<MP; m2+=256){
    float s = redk[0][m2]+redk[1][m2]+redk[2][m2]+redk[3][m2];
    ksump[((size_t)(h*NB+bb))*MP + m2] = s;
  }
  if (tid==0){
    float bm = fmaxf(fmaxf(redm[0],redm[1]), fmaxf(redm[2],redm[3]));
    u32 b = __float_as_uint(bm);
    u32 enc = (b & 0x80000000u) ? ~b : (b | 0x80000000u);
    atomicMax(kmaxg + h, enc);
  }
}

// ---------------- K3b: reduce partials + apply max/EPS correction ----------------
__global__ void k_reduce(const float* __restrict__ ctxp, const float* __restrict__ ksump,
                         const u32* __restrict__ kmaxg, const float* __restrict__ vcs,
                         u16* __restrict__ ctxT, float* __restrict__ ksum, int n)
{
  const int T1 = NH*MP*64;
  int idx = blockIdx.x*256 + threadIdx.x;
  if (idx < T1){
    int h = idx/(MP*64), r = idx - h*MP*64, m = r>>6, d = r&63;
    u32 ee = kmaxg[h]; u32 b = (ee & 0x80000000u) ? (ee ^ 0x80000000u) : ~ee;
    float sc = __expf(-__uint_as_float(b));
    float s = 0.f;
    for (int bb=0; bb<NB; ++bb) s += ctxp[(((size_t)(h*NB+bb))*MP + m)*64 + d];
    float val = (m < MF) ? (sc*s + REPS*vcs[h*64 + d]) : 0.f;
    ctxT[((size_t)h*64 + d)*MP + m] = f2bf(val);
  } else if (idx < T1 + NH*MP){
    int k2 = idx - T1, h = k2/MP, m = k2 - h*MP;
    u32 ee = kmaxg[h]; u32 b = (ee & 0x80000000u) ? (ee ^ 0x80000000u) : ~ee;
    float sc = __expf(-__uint_as_float(b));
    float s = 0.f;
    for (int bb=0; bb<NB; ++bb) s += ksump[((size_t)(h*NB+bb))*MP + m];
    ksum[h*MP + m] = (m < MF) ? (sc*s + REPS*(float)n) : 0.f;
  }
}

// ---------------- K4: query path (MFMA, proj staged in LDS, grid-stride tiles) ----------------
__global__ __launch_bounds__(256) void k_qattn(
    const u16* __restrict__ Qb, const u16* __restrict__ projp,
    const u16* __restrict__ ctxT, const float* __restrict__ ksum,
    u16* __restrict__ trans, int n)
{
  __shared__ u32 pj[288*32];              // swizzled proj (36864 B)
  __shared__ u16 qp_lds[4][16][168];      // per-wave qp half (21504 B)
  const int tid = threadIdx.x;
  const int w = tid>>6, l = tid&63;
  const int h = blockIdx.y;
  const int lm = l&15, lk = l>>4;
  #pragma unroll
  for (int q=0; q<9; ++q){
    int cix = q*256 + tid;
    int row = cix>>3, c4 = (cix&7)*4;
    uint4 v = *(const uint4*)(projp + row*64 + c4*2);
    *(uint4*)&pj[row*32 + (c4 ^ ((row&7)<<2))] = v;
  }
  float ksm[18];
  #pragma unroll
  for (int mt=0;mt<18;++mt) ksm[mt] = ksum[h*MP + mt*16 + lm];
  __syncthreads();
  const int ntile = (n+63)>>6;
  #pragma unroll 1
  for (int t = blockIdx.x; t < ntile; t += NBQ){
    const int nb = t*64 + w*16;
    int rr = nb + lm; if (rr > n-1) rr = n-1;
    const u16* Qbase = Qb + (((size_t)h*n + rr)<<6);
    bf16x8 af0 = *(const bf16x8*)(Qbase + lk*8);
    bf16x8 af1 = *(const bf16x8*)(Qbase + 32 + lk*8);
    float dg = 0.f;
    #pragma unroll
    for (int i2=0;i2<8;i2++){
      float a = bf2f(((const u16*)&af0)[i2]);
      float b = bf2f(((const u16*)&af1)[i2]);
      dg += a*a + b*b;
    }
    dg += __shfl_xor(dg,16); dg += __shfl_xor(dg,32);
    dg *= 0.0625f;
    float dgr[4];
    #pragma unroll
    for (int j=0;j<4;j++) dgr[j] = __shfl(dg, lk*4+j, 16);
    f32x4 D[18];
    #pragma unroll
    for (int mt=0;mt<18;++mt){
      const int m = mt*16 + lm;
      bf16x8 b0 = *(const bf16x8*)&pj[m*32 + ((lk*4) ^ ((m&7)<<2))];
      bf16x8 b1 = *(const bf16x8*)&pj[m*32 + ((16 + lk*4) ^ ((m&7)<<2))];
      f32x4 z = {0,0,0,0};
      z = MFMA16(af0, b0, z);
      z = MFMA16(af1, b1, z);
      D[mt] = z;
    }
    float rmax[4] = {-3.0e38f,-3.0e38f,-3.0e38f,-3.0e38f};
    #pragma unroll
    for (int mt=0;mt<17;++mt){
      const bool vm = (mt<16) || (lm<10);
      #pragma unroll
      for (int j=0;j<4;j++){
        float dd = DN*D[mt][j];
        if (vm) rmax[j] = fmaxf(rmax[j], dd);
      }
    }
    #pragma unroll
    for (int j=0;j<4;j++){
      #pragma unroll
      for (int s=1;s<16;s<<=1) rmax[j] = fmaxf(rmax[j], __shfl_xor(rmax[j], s));
    }
    float den[4] = {0,0,0,0};
    f32x4 o[4] = {{0,0,0,0},{0,0,0,0},{0,0,0,0},{0,0,0,0}};
    #pragma unroll
    for (int mt=0;mt<10;++mt){
      #pragma unroll
      for (int j=0;j<4;j++){
        float qp = RATIO*(__expf(DN*D[mt][j] - dgr[j] - rmax[j]) + EPSRF);
        den[j] += qp * ksm[mt];
        qp_lds[w][lk*4+j][mt*16+lm] = f2bf(qp);
      }
    }
    #pragma unroll
    for (int ks=0;ks<5;++ks){
      bf16x8 av = *(const bf16x8*)&qp_lds[w][lm][ks*32 + lk*8];
      #pragma unroll
      for (int dt=0;dt<4;++dt){
        bf16x8 bv = *(const bf16x8*)(ctxT + (size_t)(h*64 + dt*16 + lm)*MP + ks*32 + lk*8);
        o[dt] = MFMA16(av, bv, o[dt]);
      }
    }
    #pragma unroll
    for (int mt=10;mt<18;++mt){
      #pragma unroll
      for (int j=0;j<4;j++){
        float qp = RATIO*(__expf(DN*D[mt][j] - dgr[j] - rmax[j]) + EPSRF);
        den[j] += qp * ksm[mt];
        qp_lds[w][lk*4+j][(mt-10)*16+lm] = f2bf(qp);
      }
    }
    #pragma unroll
    for (int ks=5;ks<9;++ks){
      bf16x8 av = *(const bf16x8*)&qp_lds[w][lm][(ks-5)*32 + lk*8];
      #pragma unroll
      for (int dt=0;dt<4;++dt){
        bf16x8 bv = *(const bf16x8*)(ctxT + (size_t)(h*64 + dt*16 + lm)*MP + ks*32 + lk*8);
        o[dt] = MFMA16(av, bv, o[dt]);
      }
    }
    #pragma unroll
    for (int j=0;j<4;j++){
      #pragma unroll
      for (int s=1;s<16;s<<=1) den[j] += __shfl_xor(den[j], s);
    }
    #pragma unroll
    for (int j=0;j<4;j++){
      const int node = nb + lk*4 + j;
      if (node < n){
        const float dv = 1.f/den[j];
        #pragma unroll
        for (int dt=0;dt<4;++dt)
          trans[(size_t)node*256 + h*64 + dt*16 + lm] = f2bf(o[dt][j]*dv);
      }
    }
  }
}

// ---------------- K5: cat -> elu -> lin2 -> elu (MFMA) ----------------
__global__ __launch_bounds__(256) void k_gnn2(
    const u16* __restrict__ G1, const u16* __restrict__ trans,
    const u16* __restrict__ l2wb, const float* __restrict__ l2b,
    u16* __restrict__ xb0, int n)
{
  __shared__ u32 cat[64*256];   // 64 nodes x 512 bf16, swizzled
  const int tid = threadIdx.x;
  const int w = tid>>6, l = tid&63;
  const int lm = l&15, lk = l>>4;
  const int n0 = blockIdx.x*64;
  #pragma unroll
  for (int src=0; src<2; ++src){
    const u16* S = src ? trans : G1;
    #pragma unroll
    for (int q=0;q<8;++q){
      int idx = q*256 + tid;
      int row = idx>>5, v8 = idx&31;
      int rr = n0+row; if (rr > n-1) rr = n-1;
      uint4 raw = *(const uint4*)(S + (size_t)rr*256 + v8*8);
      const u16* p = (const u16*)&raw;
      u32 o2[4];
      #pragma unroll
      for (int t2=0;t2<4;++t2)
        o2[t2] = pack2bf(eluf(bf2f(p[t2*2])), eluf(bf2f(p[t2*2+1])));
      int word = (v8*4 + src*128) ^ ((row&7)<<2);
      *(uint4*)&cat[row*256 + word] = *(uint4*)o2;
    }
  }
  __syncthreads();
  f32x4 acc[2] = {{0,0,0,0},{0,0,0,0}};
  const int rowl = w*16 + lm;
  #pragma unroll 4
  for (int kt=0; kt<16; ++kt){
    bf16x8 a = *(const bf16x8*)&cat[rowl*256 + ((kt*16 + lk*4) ^ ((rowl&7)<<2))];
    #pragma unroll
    for (int jj=0;jj<2;++jj){
      bf16x8 b = *(const bf16x8*)(l2wb + (size_t)(jj*16+lm)*512 + kt*32 + lk*8);
      acc[jj] = MFMA16(a, b, acc[jj]);
    }
  }
  #pragma unroll
  for (int jj=0;jj<2;++jj){
    const int o = jj*16 + lm;
    const float bias = l2b[o];
    #pragma unroll
    for (int jr=0;jr<4;++jr){
      const int node = n0 + w*16 + lk*4 + jr;
      if (node < n)
        xb0[(size_t)node*32 + o] = f2bf(eluf(acc[jj][jr] + bias));
    }
  }
}

// ---------------- edge layout detect ----------------
__global__ void k_edgemode(const int* __restrict__ ei, int* __restrict__ mode){
  __shared__ int any;
  if (threadIdx.x==0) any = 0;
  __syncthreads();
  if (ei[threadIdx.x*2+1] != 0) any = 1;
  __syncthreads();
  if (threadIdx.x==0) *mode = any;
}
__device__ __forceinline__ int edge_at(const int* ei, int mode, size_t idx){
  if (mode) return ei[idx];
  return (int)((const long long*)ei)[idx];
}

// ---------------- CSR build ----------------
__global__ void k_hist(const int* __restrict__ ei, const int* __restrict__ mode,
                       u32* __restrict__ deg, int e){
  const int md = *mode;
  for (size_t i = (size_t)blockIdx.x*blockDim.x + threadIdx.x; i < (size_t)e; i += (size_t)gridDim.x*blockDim.x)
    atomicAdd(&deg[edge_at(ei, md, (size_t)e + i)], 1u);
}
__global__ void k_dis(const u32* __restrict__ deg, float* __restrict__ dis, int n){
  int i = blockIdx.x*256 + threadIdx.x;
  if (i<n) dis[i] = rsqrtf((float)(deg[i] + 1u));
}
// ---------------- parallel prefix scan (3 kernels) ----------------
__global__ __launch_bounds__(256) void k_bsum(const u32* __restrict__ deg,
                                              u32* __restrict__ bsum, int n){
  __shared__ u32 red[4];
  const int tid = threadIdx.x, lane = tid&63, wv = tid>>6;
  const int base = blockIdx.x*1024;
  u32 s = 0;
  #pragma unroll
  for (int q=0;q<4;++q){
    int i = base + q*256 + tid;
    if (i<n) s += deg[i];
  }
  #pragma unroll
  for (int off=1; off<64; off<<=1) s += __shfl_xor(s, off, 64);
  if (lane==0) red[wv] = s;
  __syncthreads();
  if (tid==0) bsum[blockIdx.x] = red[0]+red[1]+red[2]+red[3];
}
__global__ __launch_bounds__(1024) void k_bscan(u32* __restrict__ bsum,
                                                u32* __restrict__ rowp, int nblk){
  __shared__ u32 wsum[16];
  __shared__ u32 carry;
  const int tid = threadIdx.x, lane = tid&63, wv = tid>>6;
  if (tid==0){ carry = 0u; rowp[0] = 0u; }
  __syncthreads();
  for (int base=0; base<nblk; base+=1024){
    int i = base + tid;
    u32 v = (i<nblk)? bsum[i] : 0u;
    u32 s = v;
    #pragma unroll
    for (int off=1; off<64; off<<=1){
      u32 t = __shfl_up(s, off, 64);
      if (lane >= off) s += t;
    }
    if (lane==63) wsum[wv] = s;
    __syncthreads();
    if (wv==0){
      u32 ws = (lane<16)? wsum[lane] : 0u;
      #pragma unroll
      for (int off=1; off<16; off<<=1){
        u32 t = __shfl_up(ws, off, 64);
        if (lane >= off) ws += t;
      }
      if (lane<16) wsum[lane] = ws;
    }
    __syncthreads();
    if (i<nblk) bsum[i] = carry + (wv ? wsum[wv-1] : 0u) + s - v;  // exclusive
    __syncthreads();
    if (tid==0) carry += wsum[15];
    __syncthreads();
  }
}
__global__ __launch_bounds__(1024) void k_scan2(const u32* __restrict__ deg,
                                                const u32* __restrict__ bsum,
                                                u32* __restrict__ rowp,
                                                u32* __restrict__ cur, int n){
  __shared__ u32 wsum[16];
  const int tid = threadIdx.x, lane = tid&63, wv = tid>>6;
  const int i = blockIdx.x*1024 + tid;
  u32 v = (i<n)? deg[i] : 0u;
  u32 s = v;
  #pragma unroll
  for (int off=1; off<64; off<<=1){
    u32 t = __shfl_up(s, off, 64);
    if (lane >= off) s += t;
  }
  if (lane==63) wsum[wv] = s;
  __syncthreads();
  if (wv==0){
    u32 ws = (lane<16)? wsum[lane] : 0u;
    #pragma unroll
    for (int off=1; off<16; off<<=1){
      u32 t = __shfl_up(ws, off, 64);
      if (lane >= off) ws += t;
    }
    if (lane<16) wsum[lane] = ws;
  }
  __syncthreads();
  if (i<n){
    u32 inc = bsum[blockIdx.x] + (wv ? wsum[wv-1] : 0u) + s;
    rowp[i+1] = inc;
    cur[i] = inc - v;     // exclusive (row start)
  }
}
__global__ void k_fill(const int* __restrict__ ei, const int* __restrict__ mode,
                       const float* __restrict__ dis,
                       u32* __restrict__ cur, uint2* __restrict__ cw, int e){
  const int md = *mode;
  for (size_t i = (size_t)blockIdx.x*blockDim.x + threadIdx.x; i < (size_t)e; i += (size_t)gridDim.x*blockDim.x){
    int s = edge_at(ei, md, i);
    int t = edge_at(ei, md, (size_t)e + i);
    u32 pos = atomicAdd(&cur[t], 1u);
    cw[pos] = make_uint2((u32)s, __float_as_uint(dis[s]*dis[t]));
  }
}

// ---------------- APPNP iteration (8 lanes/node, 8-edge unroll for gather ILP) ----------------
__global__ __launch_bounds__(256) void k_appnp(
    const u16* __restrict__ xin, const u16* __restrict__ hb16,
    u16* __restrict__ xout, const u32* __restrict__ rowp,
    const uint2* __restrict__ cw, const float* __restrict__ dis, int n)
{
  const int g = threadIdx.x>>3, j4 = threadIdx.x&7;
  const int node = blockIdx.x*32 + g;
  if (node >= n) return;
  const uint2* x64 = (const uint2*)xin;
  float d0 = dis[node];
  float dd = d0*d0;
  uint2 xv = x64[((size_t)node<<3) + j4];
  float a0 = dd*bf2f((u16)xv.x), a1 = dd*bf2f((u16)(xv.x>>16));
  float a2 = dd*bf2f((u16)xv.y), a3 = dd*bf2f((u16)(xv.y>>16));
  u32 r0 = rowp[node], r1 = rowp[node+1];
  u32 k = r0;
  for (; k+8 <= r1; k += 8){
    uint2 e0=cw[k],e1=cw[k+1],e2=cw[k+2],e3=cw[k+3],e4=cw[k+4],e5=cw[k+5],e6=cw[k+6],e7=cw[k+7];
    uint2 v0=x64[((size_t)e0.x<<3)+j4], v1=x64[((size_t)e1.x<<3)+j4];
    uint2 v2=x64[((size_t)e2.x<<3)+j4], v3=x64[((size_t)e3.x<<3)+j4];
    uint2 v4=x64[((size_t)e4.x<<3)+j4], v5=x64[((size_t)e5.x<<3)+j4];
    uint2 v6=x64[((size_t)e6.x<<3)+j4], v7=x64[((size_t)e7.x<<3)+j4];
    float w0=__uint_as_float(e0.y), w1=__uint_as_float(e1.y);
    float w2=__uint_as_float(e2.y), w3=__uint_as_float(e3.y);
    float w4=__uint_as_float(e4.y), w5=__uint_as_float(e5.y);
    float w6=__uint_as_float(e6.y), w7=__uint_as_float(e7.y);
    a0 += w0*bf2f((u16)v0.x) + w1*bf2f((u16)v1.x) + w2*bf2f((u16)v2.x) + w3*bf2f((u16)v3.x)
        + w4*bf2f((u16)v4.x) + w5*bf2f((u16)v5.x) + w6*bf2f((u16)v6.x) + w7*bf2f((u16)v7.x);
    a1 += w0*bf2f((u16)(v0.x>>16)) + w1*bf2f((u16)(v1.x>>16)) + w2*bf2f((u16)(v2.x>>16)) + w3*bf2f((u16)(v3.x>>16))
        + w4*bf2f((u16)(v4.x>>16)) + w5*bf2f((u16)(v5.x>>16)) + w6*bf2f((u16)(v6.x>>16)) + w7*bf2f((u16)(v7.x>>16));
    a2 += w0*bf2f((u16)v0.y) + w1*bf2f((u16)v1.y) + w2*bf2f((u16)v2.y) + w3*bf2f((u16)v3.y)
        + w4*bf2f((u16)v4.y) + w5*bf2f((u16)v5.y) + w6*bf2f((u16)v6.y) + w7*bf2f((u16)v7.y);
    a3 += w0*bf2f((u16)(v0.y>>16)) + w1*bf2f((u16)(v1.y>>16)) + w2*bf2f((u16)(v2.y>>16)) + w3*bf2f((u16)(v3.y>>16))
        + w4*bf2f((u16)(v4.y>>16)) + w5*bf2f((u16)(v5.y>>16)) + w6*bf2f((u16)(v6.y>>16)) + w7*bf2f((u16)(v7.y>>16));
  }
  for (; k < r1; ++k){
    uint2 e = cw[k];
    uint2 v = x64[((size_t)e.x<<3)+j4];
    float wgt = __uint_as_float(e.y);
    a0 += wgt*bf2f((u16)v.x);
    a1 += wgt*bf2f((u16)(v.x>>16));
    a2 += wgt*bf2f((u16)v.y);
    a3 += wgt*bf2f((u16)(v.y>>16));
  }
  uint2 hv = ((const uint2*)hb16)[((size_t)node<<3) + j4];
  uint2 o;
  o.x = pack2bf(0.9f*a0 + 0.1f*bf2f((u16)hv.x), 0.9f*a1 + 0.1f*bf2f((u16)(hv.x>>16)));
  o.y = pack2bf(0.9f*a2 + 0.1f*bf2f((u16)hv.y), 0.9f*a3 + 0.1f*bf2f((u16)(hv.y>>16)));
  ((uint2*)xout)[((size_t)node<<3) + j4] = o;
}

// ---------------- final APPNP iteration fused with log_softmax + raw write ----------------
__global__ __launch_bounds__(256) void k_appnp_lsm(
    const u16* __restrict__ xin, const u16* __restrict__ hb16,
    float* __restrict__ out, const u32* __restrict__ rowp,
    const uint2* __restrict__ cw, const float* __restrict__ dis, int n)
{
  const int g = threadIdx.x>>3, j4 = threadIdx.x&7;
  const int node = blockIdx.x*32 + g;
  if (node >= n) return;
  const uint2* x64 = (const uint2*)xin;
  float d0 = dis[node];
  float dd = d0*d0;
  uint2 xv = x64[((size_t)node<<3) + j4];
  float a0 = dd*bf2f((u16)xv.x), a1 = dd*bf2f((u16)(xv.x>>16));
  float a2 = dd*bf2f((u16)xv.y), a3 = dd*bf2f((u16)(xv.y>>16));
  u32 r0 = rowp[node], r1 = rowp[node+1];
  u32 k = r0;
  for (; k+8 <= r1; k += 8){
    uint2 e0=cw[k],e1=cw[k+1],e2=cw[k+2],e3=cw[k+3],e4=cw[k+4],e5=cw[k+5],e6=cw[k+6],e7=cw[k+7];
    uint2 v0=x64[((size_t)e0.x<<3)+j4], v1=x64[((size_t)e1.x<<3)+j4];
    uint2 v2=x64[((size_t)e2.x<<3)+j4], v3=x64[((size_t)e3.x<<3)+j4];
    uint2 v4=x64[((size_t)e4.x<<3)+j4], v5=x64[((size_t)e5.x<<3)+j4];
    uint2 v6=x64[((size_t)e6.x<<3)+j4], v7=x64[((size_t)e7.x<<3)+j4];
    float w0=__uint_as_float(e0.y), w1=__uint_as_float(e1.y);
    float w2=__uint_as_float(e2.y), w3=__uint_as_float(e3.y);
    float w4=__uint_as_float(e4.y), w5=__uint_as_float(e5.y);
    float w6=__uint_as_float(e6.y), w7=__uint_as_float(e7.y);
    a0 += w0*bf2f((u16)v0.x) + w1*bf2f((u16)v1.x) + w2*bf2f((u16)v2.x) + w3*bf2f((u16)v3.x)
        + w4*bf2f((u16)v4.x) + w5*bf2f((u16)v5.x) + w6*bf2f((u16)v6.x) + w7*bf2f((u16)v7.x);
    a1 += w0*bf2f((u16)(v0.x>>16)) + w1*bf2f((u16)(v1.x>>16)) + w2*bf2f((u16)(v2.x>>16)) + w3*bf2f((u16)(v3.x>>16))
        + w4*bf2f((u16)(v4.x>>16)) + w5*bf2f((u16)(v5.x>>16)) + w6*bf2f((u16)(v6.x>>16)) + w7*bf2f((u16)(v7.x>>16));
    a2 += w0*bf2f((u16)v0.y) + w1*bf2f((u16)v1.y) + w2*bf2f((u16)v2.y) + w3*bf2f((u16)v3.y)
        + w4*bf2f((u16)v4.y) + w5*bf2f((u16)v5.y) + w6*bf2f((u16)v6.y) + w7*bf2f((u16)v7.y);
    a3 += w0*bf2f((u16)(v0.y>>16)) + w1*bf2f((u16)(v1.y>>16)) + w2*bf2f((u16)(v2.y>>16)) + w3*bf2f((u16)(v3.y>>16))
        + w4*bf2f((u16)(v4.y>>16)) + w5*bf2f((u16)(v5.y>>16)) + w6*bf2f((u16)(v6.y>>16)) + w7*bf2f((u16)(v7.y>>16));
  }
  for (; k < r1; ++k){
    uint2 e = cw[k];
    uint2 v = x64[((size_t)e.x<<3)+j4];
    float wgt = __uint_as_float(e.y);
    a0 += wgt*bf2f((u16)v.x);
    a1 += wgt*bf2f((u16)(v.x>>16));
    a2 += wgt*bf2f((u16)v.y);
    a3 += wgt*bf2f((u16)(v.y>>16));
  }
  uint2 hv = ((const uint2*)hb16)[((size_t)node<<3) + j4];
  float v0 = 0.9f*a0 + 0.1f*bf2f((u16)hv.x);
  float v1 = 0.9f*a1 + 0.1f*bf2f((u16)(hv.x>>16));
  float v2 = 0.9f*a2 + 0.1f*bf2f((u16)hv.y);
  float v3 = 0.9f*a3 + 0.1f*bf2f((u16)(hv.y>>16));
  float m = fmaxf(fmaxf(v0,v1), fmaxf(v2,v3));
  #pragma unroll
  for (int o2=1;o2<8;o2<<=1) m = fmaxf(m, __shfl_xor(m, o2, 8));
  float s = __expf(v0-m)+__expf(v1-m)+__expf(v2-m)+__expf(v3-m);
  #pragma unroll
  for (int o2=1;o2<8;o2<<=1) s += __shfl_xor(s, o2, 8);
  float ls = m + logf(s);
  float4 lsv = make_float4(v0-ls, v1-ls, v2-ls, v3-ls);
  *(float4*)(out + (size_t)node*32 + j4*4) = lsv;
  float4 raw = make_float4(v0, v1, v2, v3);
  *(float4*)(out + (size_t)n*32 + (size_t)node*32 + j4*4) = raw;
}

extern "C" void kernel_launch(void* const* d_in, const int* in_sizes, int n_in,
                              void* d_out, int out_size, void* d_ws, size_t ws_size,
                              hipStream_t stream)
{
  const float* x   = (const float*)d_in[0];
  const int*   ei  = (const int*)  d_in[1];
  const float* l1w = (const float*)d_in[2];
  const float* l1b = (const float*)d_in[3];
  const float* l2w = (const float*)d_in[4];
  const float* l2b = (const float*)d_in[5];
  const float* qw  = (const float*)d_in[6];
  const float* qb  = (const float*)d_in[7];
  const float* kw  = (const float*)d_in[8];
  const float* kb  = (const float*)d_in[9];
  const float* vw  = (const float*)d_in[10];
  const float* vb  = (const float*)d_in[11];
  const float* proj= (const float*)d_in[12];
  const int n = in_sizes[0] / 256;
  const int e = in_sizes[1] / 2;

  char* ws = (char*)d_ws;
  auto au = [](size_t v){ return (v + 255) & ~(size_t)255; };
  const size_t bQ = (size_t)n * 512;
  const size_t oQ = 0;
  const size_t oK = au(oQ + bQ);
  const size_t oV = au(oK + bQ);
  const size_t oG1 = au(oV + bQ);
  const size_t oCtxp = au(oG1 + bQ);
  const size_t bCtxp = (size_t)NH*NB*MP*64*4;
  const size_t oKsump = au(oCtxp + bCtxp);
  const size_t bKsump = (size_t)NH*NB*MP*4;
  const size_t oCtxT = au(oKsump + bKsump);
  const size_t oKsum = au(oCtxT + (size_t)NH*64*MP*2);
  const size_t oKmax = au(oKsum + (size_t)NH*MP*4);
  const size_t oVcs  = oKmax + 256;
  const size_t oMode = oVcs + 1024;
  const size_t oL2wb = au(oMode + 256);
  const size_t oWb   = au(oL2wb + 32768);
  const size_t oProjp= au(oWb + (size_t)1024*256*2);
  const size_t oTrans = oK;
  const size_t oG2 = oQ;
  const size_t oXb0 = au(oG2 + (size_t)n*32*4);
  const size_t oXbA = au(oXb0 + (size_t)n*32*2);
  const size_t oXbB = au(oXbA + (size_t)n*32*2);
  const size_t oDeg = au(oXbB + (size_t)n*32*2);
  const size_t oDis = au(oDeg + (size_t)n*4);
  const size_t oRowp= au(oDis + (size_t)n*4);
  const size_t oCur = au(oRowp + (size_t)(n+1)*4);
  const size_t oBsum= au(oCur + (size_t)(n+1)*4);
  const size_t oCw  = oV;
  (void)ws_size; (void)n_in; (void)out_size;

  u16* Q  = (u16*)(ws + oQ);
  u16* Kb = (u16*)(ws + oK);
  u16* Vb = (u16*)(ws + oV);
  u16* G1 = (u16*)(ws + oG1);
  float* ctxp = (float*)(ws + oCtxp);
  float* ksump= (float*)(ws + oKsump);
  u16*  ctxT  = (u16*)(ws + oCtxT);
  float* ksum = (float*)(ws + oKsum);
  u32*  kmax  = (u32*)(ws + oKmax);
  float* Vcs  = (float*)(ws + oVcs);
  int*  mode  = (int*)(ws + oMode);
  u16*  l2wb  = (u16*)(ws + oL2wb);
  u16*  Wb    = (u16*)(ws + oWb);
  u16*  projp = (u16*)(ws + oProjp);
  u16* trans  = (u16*)(ws + oTrans);
  u16* xb0    = (u16*)(ws + oXb0);
  u16* xbA    = (u16*)(ws + oXbA);
  u16* xbB    = (u16*)(ws + oXbB);
  u32* deg    = (u32*)(ws + oDeg);
  float* dis  = (float*)(ws + oDis);
  u32* rowp   = (u32*)(ws + oRowp);
  u32* cur    = (u32*)(ws + oCur);
  u32* bsum   = (u32*)(ws + oBsum);
  uint2* cw   = (uint2*)(ws + oCw);

  k_cvtw<<<1024,256,0,stream>>>(qw,kw,vw,l1w,l2w,proj,Wb,projp,l2wb);
  k_proj<<<(n+127)/128,512,0,stream>>>(x,Wb,qb,kb,vb,l1b,Q,Kb,Vb,G1,n);
  hipMemsetAsync(ws + oKmax, 0, 16, stream);
  hipMemsetAsync(ws + oVcs, 0, 1024, stream);
  k_vcs<<<dim3(64,4),256,0,stream>>>(Vb,Vcs,n);
  k_ctx<<<dim3(NB,NH),256,0,stream>>>(Kb,Vb,projp,ctxp,ksump,kmax,n);
  {
    int tot = NH*MP*64 + NH*MP;
    k_reduce<<<(tot+255)/256,256,0,stream>>>(ctxp,ksump,kmax,Vcs,ctxT,ksum,n);
  }
  k_qattn<<<dim3(NBQ,4),256,0,stream>>>(Q,projp,ctxT,ksum,trans,n);
  k_gnn2<<<(n+63)/64,256,0,stream>>>(G1,trans,l2wb,l2b,xb0,n);
  // ---- APPNP ----
  k_edgemode<<<1,256,0,stream>>>(ei,mode);
  hipMemsetAsync(ws + oDeg, 0, (size_t)n*4, stream);
  k_hist<<<2048,256,0,stream>>>(ei,mode,deg,e);
  k_dis<<<(n+255)/256,256,0,stream>>>(deg,dis,n);
  {
    const int nblk = (n+1023)/1024;
    k_bsum<<<nblk,256,0,stream>>>(deg,bsum,n);
    k_bscan<<<1,1024,0,stream>>>(bsum,rowp,nblk);
    k_scan2<<<nblk,1024,0,stream>>>(deg,bsum,rowp,cur,n);
  }
  k_fill<<<2048,256,0,stream>>>(ei,mode,dis,cur,cw,e);
  const u16* curx = xb0;
  u16* bufs[2] = {xbA, xbB};
  for (int it=0; it<9; ++it){
    u16* nxt = bufs[it&1];
    k_appnp<<<(n+31)/32,256,0,stream>>>(curx,xb0,nxt,rowp,cw,dis,n);
    curx = nxt;
  }
  k_appnp_lsm<<<(n+31)/32,256,0,stream>>>(curx,xb0,(float*)d_out,rowp,cw,dis,n);
}